// Round 1
// baseline (1207.771 us; speedup 1.0000x reference)
//
#include <hip/hip_runtime.h>

#define DD 128
#define SS 1024
#define BB 4
#define M_TOT 20000
#define M_PAD 20032   // 313*64

// ---------------- init: zero G and ti ----------------
__global__ void k_init(float* __restrict__ Gmat, float* __restrict__ ti) {
    int idx = blockIdx.x * 256 + threadIdx.x;
    if (idx < BB * DD * DD) Gmat[idx] = 0.0f;
    if (idx < BB) ti[idx] = 0.0f;
}

// ---------------- prep: normalized mem rows + norm_sq (padded to M_PAD) ----------------
__global__ __launch_bounds__(256) void k_prep_mem(const float* __restrict__ mem,
                                                  float* __restrict__ mn,
                                                  float* __restrict__ norm_sq) {
    int wave = threadIdx.x >> 6;
    int lane = threadIdx.x & 63;
    int row = blockIdx.x * 4 + wave;
    float2 v = make_float2(0.f, 0.f);
    if (row < M_TOT) v = *(const float2*)(mem + row * DD + lane * 2);
    float ss = v.x * v.x + v.y * v.y;
    #pragma unroll
    for (int off = 1; off < 64; off <<= 1) ss += __shfl_xor(ss, off);
    float rs = rsqrtf(ss + 1e-12f);
    *(float2*)(mn + row * DD + lane * 2) = make_float2(v.x * rs, v.y * rs);
    if (lane == 0) norm_sq[row] = ss;
}

// ---------------- MLP (Linear->LN->ReLU->Linear) + x normalization ----------------
// 64 threads = 1 wave, 64 tokens per block (one token per thread).
// W accesses are wave-uniform -> scalar loads. x/h rows live in LDS (pad 33 f4).
__global__ __launch_bounds__(64) void k_mlp(
    const float* __restrict__ x, const float* __restrict__ W1,
    const float* __restrict__ b1, const float* __restrict__ ln_g,
    const float* __restrict__ ln_b, const float* __restrict__ W2,
    const float* __restrict__ b2, float* __restrict__ xn,
    float* __restrict__ raw) {
    __shared__ float4 xl[64 * 33];
    __shared__ float4 hl[64 * 33];
    const int tid = threadIdx.x;
    const int tok0 = blockIdx.x * 64;

    // cooperative coalesced load of 64 token rows
    const float4* xv = (const float4*)x + (size_t)tok0 * 32;
    #pragma unroll
    for (int i = 0; i < 32; ++i) {
        int idx = tid + i * 64;
        int r = idx >> 5, c = idx & 31;
        xl[r * 33 + c] = xv[idx];
    }
    __syncthreads();

    const float4* W1v = (const float4*)W1;
    const float4* W2v = (const float4*)W2;

    // h = x @ W1^T + b1  (4-e register blocking, scalar W loads)
    float hsum = 0.f, hsumsq = 0.f;
    #pragma unroll 1
    for (int e4 = 0; e4 < 32; ++e4) {
        float a0 = b1[e4 * 4 + 0], a1 = b1[e4 * 4 + 1];
        float a2 = b1[e4 * 4 + 2], a3 = b1[e4 * 4 + 3];
        #pragma unroll
        for (int k4 = 0; k4 < 32; ++k4) {
            float4 xr = xl[tid * 33 + k4];
            float4 w0 = W1v[(e4 * 4 + 0) * 32 + k4];
            float4 w1 = W1v[(e4 * 4 + 1) * 32 + k4];
            float4 w2 = W1v[(e4 * 4 + 2) * 32 + k4];
            float4 w3 = W1v[(e4 * 4 + 3) * 32 + k4];
            a0 += xr.x * w0.x + xr.y * w0.y + xr.z * w0.z + xr.w * w0.w;
            a1 += xr.x * w1.x + xr.y * w1.y + xr.z * w1.z + xr.w * w1.w;
            a2 += xr.x * w2.x + xr.y * w2.y + xr.z * w2.z + xr.w * w2.w;
            a3 += xr.x * w3.x + xr.y * w3.y + xr.z * w3.z + xr.w * w3.w;
        }
        hl[tid * 33 + e4] = make_float4(a0, a1, a2, a3);
        hsum += a0 + a1 + a2 + a3;
        hsumsq += a0 * a0 + a1 * a1 + a2 * a2 + a3 * a3;
    }
    float mu = hsum * (1.f / 128.f);
    float var = hsumsq * (1.f / 128.f) - mu * mu;
    float rstd = rsqrtf(var + 1e-5f);

    // feats = relu(LN(h)) in place
    #pragma unroll 1
    for (int e4 = 0; e4 < 32; ++e4) {
        float4 hv = hl[tid * 33 + e4];
        float4 gv = ((const float4*)ln_g)[e4];
        float4 bv = ((const float4*)ln_b)[e4];
        hv.x = fmaxf((hv.x - mu) * rstd * gv.x + bv.x, 0.f);
        hv.y = fmaxf((hv.y - mu) * rstd * gv.y + bv.y, 0.f);
        hv.z = fmaxf((hv.z - mu) * rstd * gv.z + bv.z, 0.f);
        hv.w = fmaxf((hv.w - mu) * rstd * gv.w + bv.w, 0.f);
        hl[tid * 33 + e4] = hv;
    }

    // xn = x * rsqrt(sum x^2 + 1e-12): scale own row in place, then coalesced writeout
    float xss = 0.f;
    #pragma unroll
    for (int k4 = 0; k4 < 32; ++k4) {
        float4 xr = xl[tid * 33 + k4];
        xss += xr.x * xr.x + xr.y * xr.y + xr.z * xr.z + xr.w * xr.w;
    }
    float xrs = rsqrtf(xss + 1e-12f);
    #pragma unroll
    for (int k4 = 0; k4 < 32; ++k4) {
        float4 xr = xl[tid * 33 + k4];
        xl[tid * 33 + k4] = make_float4(xr.x * xrs, xr.y * xrs, xr.z * xrs, xr.w * xrs);
    }
    __syncthreads();
    float4* xnv = (float4*)xn + (size_t)tok0 * 32;
    #pragma unroll
    for (int i = 0; i < 32; ++i) {
        int idx = tid + i * 64;
        int r = idx >> 5, c = idx & 31;
        xnv[idx] = xl[r * 33 + c];
    }
    __syncthreads();   // xl reads done; safe to overwrite with raw

    // raw = feats @ W2^T + b2  -> xl, then coalesced writeout
    #pragma unroll 1
    for (int e4 = 0; e4 < 32; ++e4) {
        float a0 = b2[e4 * 4 + 0], a1 = b2[e4 * 4 + 1];
        float a2 = b2[e4 * 4 + 2], a3 = b2[e4 * 4 + 3];
        #pragma unroll
        for (int k4 = 0; k4 < 32; ++k4) {
            float4 fr = hl[tid * 33 + k4];
            float4 w0 = W2v[(e4 * 4 + 0) * 32 + k4];
            float4 w1 = W2v[(e4 * 4 + 1) * 32 + k4];
            float4 w2 = W2v[(e4 * 4 + 2) * 32 + k4];
            float4 w3 = W2v[(e4 * 4 + 3) * 32 + k4];
            a0 += fr.x * w0.x + fr.y * w0.y + fr.z * w0.z + fr.w * w0.w;
            a1 += fr.x * w1.x + fr.y * w1.y + fr.z * w1.z + fr.w * w1.w;
            a2 += fr.x * w2.x + fr.y * w2.y + fr.z * w2.z + fr.w * w2.w;
            a3 += fr.x * w3.x + fr.y * w3.y + fr.z * w3.z + fr.w * w3.w;
        }
        xl[tid * 33 + e4] = make_float4(a0, a1, a2, a3);
    }
    __syncthreads();
    float4* rawv = (float4*)raw + (size_t)tok0 * 32;
    #pragma unroll
    for (int i = 0; i < 32; ++i) {
        int idx = tid + i * 64;
        int r = idx >> 5, c = idx & 31;
        rawv[idx] = xl[r * 33 + c];
    }
}

// ---------------- cw[b,m] = sum_s (sim>0.1 ? sim : 0) ----------------
// block: 4 waves x 64 lanes; lane = s within group; each block owns 64 m and all S.
// mem-operand loads are wave-uniform (scalar path); acc[64] in VGPRs; no LDS tiles.
__global__ __launch_bounds__(256) void k_cw(
    const float* __restrict__ xn, const float* __restrict__ mn,
    float* __restrict__ cw) {
    __shared__ float red[64];
    const int tid = threadIdx.x;
    const int lane = tid & 63;
    const int wave = tid >> 6;
    const int b = blockIdx.y;
    const int m_base = blockIdx.x * 64;
    if (tid < 64) red[tid] = 0.0f;
    __syncthreads();

    const float4* mnv = (const float4*)(mn + (size_t)m_base * DD);
    const float4* xnv = (const float4*)(xn + (size_t)b * SS * DD);

    #pragma unroll 1
    for (int si = 0; si < 4; ++si) {
        const int s = si * 256 + wave * 64 + lane;
        float acc[64];
        #pragma unroll
        for (int m = 0; m < 64; ++m) acc[m] = 0.0f;

        #pragma unroll 1
        for (int kc = 0; kc < 4; ++kc) {
            float4 xk[8];
            #pragma unroll
            for (int k4 = 0; k4 < 8; ++k4) xk[k4] = xnv[s * 32 + kc * 8 + k4];
            #pragma unroll
            for (int m = 0; m < 64; ++m) {
                #pragma unroll
                for (int k4 = 0; k4 < 8; ++k4) {
                    float4 w = mnv[m * 32 + kc * 8 + k4];
                    acc[m] += xk[k4].x * w.x + xk[k4].y * w.y +
                              xk[k4].z * w.z + xk[k4].w * w.w;
                }
            }
        }
        #pragma unroll
        for (int m = 0; m < 64; ++m) {
            float t = acc[m] > 0.1f ? acc[m] : 0.0f;
            #pragma unroll
            for (int off = 1; off < 64; off <<= 1) t += __shfl_xor(t, off);
            if (lane == 0) atomicAdd(&red[m], t);
        }
    }
    __syncthreads();
    if (tid < 64) cw[(size_t)b * M_PAD + m_base + tid] = red[tid];
}

// ---------------- gates: g = eff/safe_ns, ti = sum eff ----------------
__global__ __launch_bounds__(256) void k_gate(
    const float* __restrict__ cw, const float* __restrict__ norm_sq,
    float* __restrict__ g, float* __restrict__ ti) {
    const int b = blockIdx.y;
    const int idx = blockIdx.x * 256 + threadIdx.x;
    float e = 0.0f;
    if (idx < M_TOT) {
        float c = cw[(size_t)b * M_PAD + idx];
        float ns = norm_sq[idx];
        bool act = (c > 0.01f) && (ns > 1e-6f);
        e = act ? c : 0.0f;
        float sns = (ns > 1e-6f) ? ns : 1.0f;
        g[(size_t)b * M_PAD + idx] = e / sns;
    }
    __shared__ float rbuf[4];
    float t = e;
    #pragma unroll
    for (int off = 1; off < 64; off <<= 1) t += __shfl_xor(t, off);
    if ((threadIdx.x & 63) == 0) rbuf[threadIdx.x >> 6] = t;
    __syncthreads();
    if (threadIdx.x == 0) atomicAdd(&ti[b], rbuf[0] + rbuf[1] + rbuf[2] + rbuf[3]);
}

// ---------------- G_b = sum_m g[b,m] * mem[m] mem[m]^T ----------------
// 256 threads as 16x16; each thread an 8x8 tile of the 128x128 G; atomic reduce.
__global__ __launch_bounds__(256) void k_gmat(
    const float* __restrict__ mem, const float* __restrict__ g,
    float* __restrict__ Gmat) {
    __shared__ float4 rows[16 * 33];
    __shared__ float gl[16];
    const int tid = threadIdx.x;
    const int tx = tid & 15, ty = tid >> 4;
    const int b = blockIdx.y;
    const int m0 = blockIdx.x * 320;
    float acc[8][8];
    #pragma unroll
    for (int i = 0; i < 8; ++i)
        #pragma unroll
        for (int j = 0; j < 8; ++j) acc[i][j] = 0.0f;

    for (int bt = 0; bt < 20; ++bt) {
        const int mb = m0 + bt * 16;
        __syncthreads();
        #pragma unroll
        for (int i = 0; i < 2; ++i) {
            int idx = tid + i * 256;
            int r = idx >> 5, c = idx & 31;
            int m = mb + r;
            float4 v = make_float4(0.f, 0.f, 0.f, 0.f);
            if (m < M_TOT) v = ((const float4*)mem)[(size_t)m * 32 + c];
            rows[r * 33 + c] = v;
        }
        if (tid < 16) {
            int m = mb + tid;
            gl[tid] = (m < M_TOT) ? g[(size_t)b * M_PAD + m] : 0.0f;
        }
        __syncthreads();
        #pragma unroll
        for (int r = 0; r < 16; ++r) {
            float gm = gl[r];
            float4 va = rows[r * 33 + ty * 2], vb = rows[r * 33 + ty * 2 + 1];
            float4 wa = rows[r * 33 + tx * 2], wb = rows[r * 33 + tx * 2 + 1];
            float v[8] = {va.x, va.y, va.z, va.w, vb.x, vb.y, vb.z, vb.w};
            float w[8] = {gm * wa.x, gm * wa.y, gm * wa.z, gm * wa.w,
                          gm * wb.x, gm * wb.y, gm * wb.z, gm * wb.w};
            #pragma unroll
            for (int i = 0; i < 8; ++i)
                #pragma unroll
                for (int j = 0; j < 8; ++j) acc[i][j] += v[i] * w[j];
        }
    }
    float* Gb = Gmat + (size_t)b * DD * DD;
    #pragma unroll
    for (int i = 0; i < 8; ++i)
        #pragma unroll
        for (int j = 0; j < 8; ++j)
            atomicAdd(&Gb[(ty * 8 + i) * DD + tx * 8 + j], acc[i][j]);
}

// ---------------- final = raw + scale * raw @ G_b ----------------
__global__ __launch_bounds__(256) void k_final(
    const float* __restrict__ raw, const float* __restrict__ Gmat,
    const float* __restrict__ ti, float* __restrict__ out) {
    __shared__ float Gl[DD * DD];
    __shared__ float rawl[32 * DD];
    const int tid = threadIdx.x;
    const int b = blockIdx.y;
    const int s0 = blockIdx.x * 32;
    const float4* Gv = (const float4*)(Gmat + (size_t)b * DD * DD);
    #pragma unroll
    for (int i = 0; i < 16; ++i) ((float4*)Gl)[tid + i * 256] = Gv[tid + i * 256];
    const float4* rv = (const float4*)(raw + ((size_t)b * SS + s0) * DD);
    #pragma unroll
    for (int i = 0; i < 4; ++i) ((float4*)rawl)[tid + i * 256] = rv[tid + i * 256];
    __syncthreads();
    float tib = ti[b];
    float scale = (tib > 0.01f) ? 0.5f / (tib + 1e-5f) : 0.0f;
    const int dq = tid & 31;   // 4 output dims: dq*4..dq*4+3
    const int sg = tid >> 5;   // 8 s-groups
    const float4* Gl4 = (const float4*)Gl;
    #pragma unroll 1
    for (int t = 0; t < 4; ++t) {
        int s = sg + t * 8;
        float4 acc = make_float4(0.f, 0.f, 0.f, 0.f);
        #pragma unroll
        for (int k = 0; k < DD; ++k) {
            float r = rawl[s * DD + k];
            float4 gv = Gl4[k * 32 + dq];
            acc.x += r * gv.x; acc.y += r * gv.y;
            acc.z += r * gv.z; acc.w += r * gv.w;
        }
        float4 rw = ((const float4*)rawl)[s * 32 + dq];
        float4 o = make_float4(rw.x + scale * acc.x, rw.y + scale * acc.y,
                               rw.z + scale * acc.z, rw.w + scale * acc.w);
        ((float4*)(out + ((size_t)b * SS + s0) * DD))[s * 32 + dq] = o;
    }
}

extern "C" void kernel_launch(void* const* d_in, const int* in_sizes, int n_in,
                              void* d_out, int out_size, void* d_ws, size_t ws_size,
                              hipStream_t stream) {
    const float* x   = (const float*)d_in[0];
    const float* mem = (const float*)d_in[1];
    const float* W1  = (const float*)d_in[2];
    const float* b1  = (const float*)d_in[3];
    const float* lg  = (const float*)d_in[4];
    const float* lb  = (const float*)d_in[5];
    const float* W2  = (const float*)d_in[6];
    const float* b2  = (const float*)d_in[7];
    float* out = (float*)d_out;

    float* ws      = (float*)d_ws;
    float* mn      = ws;                         // M_PAD*128
    float* norm_sq = mn + (size_t)M_PAD * DD;    // M_PAD
    float* xn      = norm_sq + M_PAD;            // B*S*D
    float* raw     = xn + (size_t)BB * SS * DD;  // B*S*D
    float* cw      = raw + (size_t)BB * SS * DD; // B*M_PAD
    float* g       = cw + (size_t)BB * M_PAD;    // B*M_PAD
    float* Gmat    = g + (size_t)BB * M_PAD;     // B*128*128
    float* ti      = Gmat + (size_t)BB * DD * DD;// B

    k_init<<<dim3(256), 256, 0, stream>>>(Gmat, ti);
    k_prep_mem<<<dim3(M_PAD / 4), 256, 0, stream>>>(mem, mn, norm_sq);
    k_mlp<<<dim3(64), 64, 0, stream>>>(x, W1, b1, lg, lb, W2, b2, xn, raw);
    k_cw<<<dim3(M_PAD / 64, BB), 256, 0, stream>>>(xn, mn, cw);
    k_gate<<<dim3((M_TOT + 255) / 256, BB), 256, 0, stream>>>(cw, norm_sq, g, ti);
    k_gmat<<<dim3(64, BB), 256, 0, stream>>>(mem, g, Gmat);
    k_final<<<dim3(SS / 32, BB), 256, 0, stream>>>(raw, Gmat, ti, out);
}

// Round 2
// 331.472 us; speedup vs baseline: 3.6437x; 3.6437x over previous
//
#include <hip/hip_runtime.h>

#define DD 128
#define SS 1024
#define BB 4
#define M_TOT 20000
#define M_PAD 20224   // 79*256

typedef __bf16 bf16x8 __attribute__((ext_vector_type(8)));
typedef float f32x16 __attribute__((ext_vector_type(16)));

__device__ __forceinline__ unsigned short f2bf(float f) {
    unsigned int u = __float_as_uint(f);
    u += 0x7FFFu + ((u >> 16) & 1u);
    return (unsigned short)(u >> 16);
}

// ---------------- init: zero G copies and ti ----------------
__global__ void k_init(float* __restrict__ Gmat, float* __restrict__ ti) {
    int idx = blockIdx.x * 256 + threadIdx.x;
    if (idx < 4 * BB * DD * DD) Gmat[idx] = 0.0f;
    if (idx < BB) ti[idx] = 0.0f;
}

// ---------------- prep: normalized mem rows (bf16) + norm_sq, padded ----------------
__global__ __launch_bounds__(256) void k_prep_mem(const float* __restrict__ mem,
                                                  unsigned short* __restrict__ mnb,
                                                  float* __restrict__ norm_sq) {
    int wv = threadIdx.x >> 6;
    int lane = threadIdx.x & 63;
    int row = blockIdx.x * 4 + wv;
    float2 v = make_float2(0.f, 0.f);
    if (row < M_TOT) v = *(const float2*)(mem + (size_t)row * DD + lane * 2);
    float ss = v.x * v.x + v.y * v.y;
    #pragma unroll
    for (int off = 1; off < 64; off <<= 1) ss += __shfl_xor(ss, off);
    float rs = rsqrtf(ss + 1e-12f);
    ushort2 o;
    o.x = f2bf(v.x * rs);
    o.y = f2bf(v.y * rs);
    *(ushort2*)(mnb + (size_t)row * DD + lane * 2) = o;
    if (lane == 0) norm_sq[row] = ss;
}

// ---------------- MLP (Linear->LN->ReLU->Linear) + xnb (bf16 normalized x) ----------------
// 256 threads: lane = token (64/block), wave = e-dim slice of 32.
__global__ __launch_bounds__(256) void k_mlp(
    const float* __restrict__ x, const float* __restrict__ W1,
    const float* __restrict__ b1, const float* __restrict__ ln_g,
    const float* __restrict__ ln_b, const float* __restrict__ W2,
    const float* __restrict__ b2, unsigned short* __restrict__ xnb,
    float* __restrict__ raw) {
    __shared__ float4 xl[64 * 33];
    __shared__ float4 hl[64 * 33];
    __shared__ float reds[4][64];
    __shared__ float redq[4][64];
    const int tid = threadIdx.x, lane = tid & 63, wv = tid >> 6;
    const int tok0 = blockIdx.x * 64;

    const float4* xv = (const float4*)x + (size_t)tok0 * 32;
    #pragma unroll
    for (int i = 0; i < 8; ++i) {
        int idx = tid + i * 256, r = idx >> 5, c = idx & 31;
        xl[r * 33 + c] = xv[idx];
    }
    __syncthreads();

    const float4* W1v = (const float4*)W1;
    float4 hreg[8];
    float hs = 0.f, hq = 0.f;
    #pragma unroll 1
    for (int e4 = 0; e4 < 8; ++e4) {
        int e = wv * 32 + e4 * 4;
        float a0 = b1[e], a1 = b1[e + 1], a2 = b1[e + 2], a3 = b1[e + 3];
        #pragma unroll
        for (int k4 = 0; k4 < 32; ++k4) {
            float4 xr = xl[lane * 33 + k4];
            float4 w0 = W1v[(size_t)(e + 0) * 32 + k4];
            float4 w1 = W1v[(size_t)(e + 1) * 32 + k4];
            float4 w2 = W1v[(size_t)(e + 2) * 32 + k4];
            float4 w3 = W1v[(size_t)(e + 3) * 32 + k4];
            a0 += xr.x * w0.x + xr.y * w0.y + xr.z * w0.z + xr.w * w0.w;
            a1 += xr.x * w1.x + xr.y * w1.y + xr.z * w1.z + xr.w * w1.w;
            a2 += xr.x * w2.x + xr.y * w2.y + xr.z * w2.z + xr.w * w2.w;
            a3 += xr.x * w3.x + xr.y * w3.y + xr.z * w3.z + xr.w * w3.w;
        }
        hreg[e4] = make_float4(a0, a1, a2, a3);
        hs += a0 + a1 + a2 + a3;
        hq += a0 * a0 + a1 * a1 + a2 * a2 + a3 * a3;
    }
    reds[wv][lane] = hs;
    redq[wv][lane] = hq;
    __syncthreads();
    float S = reds[0][lane] + reds[1][lane] + reds[2][lane] + reds[3][lane];
    float Q = redq[0][lane] + redq[1][lane] + redq[2][lane] + redq[3][lane];
    float mu = S * (1.f / 128.f);
    float rstd = rsqrtf(Q * (1.f / 128.f) - mu * mu + 1e-5f);

    // feats = relu(LN(h)) -> hl
    #pragma unroll
    for (int e4 = 0; e4 < 8; ++e4) {
        float4 hv = hreg[e4];
        float4 gv = ((const float4*)ln_g)[wv * 8 + e4];
        float4 bv = ((const float4*)ln_b)[wv * 8 + e4];
        hv.x = fmaxf((hv.x - mu) * rstd * gv.x + bv.x, 0.f);
        hv.y = fmaxf((hv.y - mu) * rstd * gv.y + bv.y, 0.f);
        hv.z = fmaxf((hv.z - mu) * rstd * gv.z + bv.z, 0.f);
        hv.w = fmaxf((hv.w - mu) * rstd * gv.w + bv.w, 0.f);
        hl[lane * 33 + wv * 8 + e4] = hv;
    }

    // xn: partial sum of squares over this wave's 32-dim slice
    float xq = 0.f;
    #pragma unroll
    for (int j = 0; j < 8; ++j) {
        float4 v = xl[lane * 33 + wv * 8 + j];
        xq += v.x * v.x + v.y * v.y + v.z * v.z + v.w * v.w;
    }
    __syncthreads();   // all reads of reds/redq done
    reds[wv][lane] = xq;
    __syncthreads();
    float XQ = reds[0][lane] + reds[1][lane] + reds[2][lane] + reds[3][lane];
    float xrs = rsqrtf(XQ + 1e-12f);
    #pragma unroll
    for (int j = 0; j < 8; ++j) {
        float4 v = xl[lane * 33 + wv * 8 + j];
        ushort4 o;
        o.x = f2bf(v.x * xrs); o.y = f2bf(v.y * xrs);
        o.z = f2bf(v.z * xrs); o.w = f2bf(v.w * xrs);
        *(ushort4*)(xnb + ((size_t)(tok0 + lane)) * DD + wv * 32 + j * 4) = o;
    }
    // hl fully written by all waves before the barrier above -> safe to read

    const float4* W2v = (const float4*)W2;
    #pragma unroll 1
    for (int e4 = 0; e4 < 8; ++e4) {
        int e = wv * 32 + e4 * 4;
        float a0 = b2[e], a1 = b2[e + 1], a2 = b2[e + 2], a3 = b2[e + 3];
        #pragma unroll
        for (int k4 = 0; k4 < 32; ++k4) {
            float4 fr = hl[lane * 33 + k4];
            float4 w0 = W2v[(size_t)(e + 0) * 32 + k4];
            float4 w1 = W2v[(size_t)(e + 1) * 32 + k4];
            float4 w2 = W2v[(size_t)(e + 2) * 32 + k4];
            float4 w3 = W2v[(size_t)(e + 3) * 32 + k4];
            a0 += fr.x * w0.x + fr.y * w0.y + fr.z * w0.z + fr.w * w0.w;
            a1 += fr.x * w1.x + fr.y * w1.y + fr.z * w1.z + fr.w * w1.w;
            a2 += fr.x * w2.x + fr.y * w2.y + fr.z * w2.z + fr.w * w2.w;
            a3 += fr.x * w3.x + fr.y * w3.y + fr.z * w3.z + fr.w * w3.w;
        }
        *(float4*)(raw + ((size_t)(tok0 + lane)) * DD + wv * 32 + e4 * 4) =
            make_float4(a0, a1, a2, a3);
    }
}

// ---------------- cw[b,m] = sum_s (sim>0.1 ? sim : 0) via bf16 MFMA ----------------
// block: 4 waves; m-tile 64 (2 col-tiles of 32, B-frags register-resident);
// wave w handles s in [w*256, w*256+256) as 8 tiles of 32. No LDS in hot loop.
__global__ __launch_bounds__(256) void k_cw(
    const unsigned short* __restrict__ xnb, const unsigned short* __restrict__ mnb,
    float* __restrict__ cw) {
    __shared__ float red[4][64];
    const int tid = threadIdx.x;
    const int lane = tid & 63, wv = tid >> 6;
    const int col = lane & 31, kh = lane >> 5;
    const int b = blockIdx.y;
    const int m0 = blockIdx.x * 64;

    bf16x8 Bf[2][8];
    const unsigned short* mp = mnb + (size_t)(m0 + col) * DD + kh * 8;
    #pragma unroll
    for (int ct = 0; ct < 2; ++ct)
        #pragma unroll
        for (int kk = 0; kk < 8; ++kk)
            Bf[ct][kk] = *(const bf16x8*)(mp + (size_t)ct * 32 * DD + kk * 16);

    float cw0 = 0.f, cw1 = 0.f;
    const unsigned short* xp = xnb + ((size_t)b * SS + wv * 256 + col) * DD + kh * 8;

    #pragma unroll 1
    for (int st = 0; st < 8; ++st) {
        bf16x8 Af[8];
        #pragma unroll
        for (int kk = 0; kk < 8; ++kk)
            Af[kk] = *(const bf16x8*)(xp + (size_t)st * 32 * DD + kk * 16);
        f32x16 a0, a1;
        #pragma unroll
        for (int r = 0; r < 16; ++r) { a0[r] = 0.f; a1[r] = 0.f; }
        #pragma unroll
        for (int kk = 0; kk < 8; ++kk) {
            a0 = __builtin_amdgcn_mfma_f32_32x32x16_bf16(Af[kk], Bf[0][kk], a0, 0, 0, 0);
            a1 = __builtin_amdgcn_mfma_f32_32x32x16_bf16(Af[kk], Bf[1][kk], a1, 0, 0, 0);
        }
        #pragma unroll
        for (int r = 0; r < 16; ++r) {
            float v0 = a0[r], v1 = a1[r];
            cw0 += v0 > 0.1f ? v0 : 0.f;
            cw1 += v1 > 0.1f ? v1 : 0.f;
        }
    }
    // rows split across lane halves -> combine
    cw0 += __shfl_xor(cw0, 32);
    cw1 += __shfl_xor(cw1, 32);
    if (lane < 32) { red[wv][col] = cw0; red[wv][col + 32] = cw1; }
    __syncthreads();
    if (tid < 64)
        cw[(size_t)b * M_PAD + m0 + tid] =
            red[0][tid] + red[1][tid] + red[2][tid] + red[3][tid];
}

// ---------------- gates: g = eff/safe_ns, ti = sum eff ----------------
__global__ __launch_bounds__(256) void k_gate(
    const float* __restrict__ cw, const float* __restrict__ norm_sq,
    float* __restrict__ g, float* __restrict__ ti) {
    const int b = blockIdx.y;
    const int idx = blockIdx.x * 256 + threadIdx.x;
    float e = 0.0f;
    if (idx < M_TOT) {
        float c = cw[(size_t)b * M_PAD + idx];
        float ns = norm_sq[idx];
        bool act = (c > 0.01f) && (ns > 1e-6f);
        e = act ? c : 0.0f;
        float sns = (ns > 1e-6f) ? ns : 1.0f;
        g[(size_t)b * M_PAD + idx] = e / sns;
    }
    __shared__ float rbuf[4];
    float t = e;
    #pragma unroll
    for (int off = 1; off < 64; off <<= 1) t += __shfl_xor(t, off);
    if ((threadIdx.x & 63) == 0) rbuf[threadIdx.x >> 6] = t;
    __syncthreads();
    if (threadIdx.x == 0) atomicAdd(&ti[b], rbuf[0] + rbuf[1] + rbuf[2] + rbuf[3]);
}

// ---------------- G_b = sum_m g[b,m] * mem[m] mem[m]^T (4-copy atomic spread) ----------------
__global__ __launch_bounds__(256) void k_gmat(
    const float* __restrict__ mem, const float* __restrict__ g,
    float* __restrict__ Gmat) {
    __shared__ float4 rows[16 * 33];
    __shared__ float gl[16];
    const int tid = threadIdx.x;
    const int tx = tid & 15, ty = tid >> 4;
    const int b = blockIdx.y;
    const int m0 = blockIdx.x * 320;
    float acc[8][8];
    #pragma unroll
    for (int i = 0; i < 8; ++i)
        #pragma unroll
        for (int j = 0; j < 8; ++j) acc[i][j] = 0.0f;

    for (int bt = 0; bt < 20; ++bt) {
        const int mb = m0 + bt * 16;
        __syncthreads();
        #pragma unroll
        for (int i = 0; i < 2; ++i) {
            int idx = tid + i * 256;
            int r = idx >> 5, c = idx & 31;
            int m = mb + r;
            float4 v = make_float4(0.f, 0.f, 0.f, 0.f);
            if (m < M_TOT) v = ((const float4*)mem)[(size_t)m * 32 + c];
            rows[r * 33 + c] = v;
        }
        if (tid < 16) {
            int m = mb + tid;
            gl[tid] = (m < M_TOT) ? g[(size_t)b * M_PAD + m] : 0.0f;
        }
        __syncthreads();
        #pragma unroll
        for (int r = 0; r < 16; ++r) {
            float gm = gl[r];
            float4 va = rows[r * 33 + ty * 2], vb = rows[r * 33 + ty * 2 + 1];
            float4 wa = rows[r * 33 + tx * 2], wb = rows[r * 33 + tx * 2 + 1];
            float v[8] = {va.x, va.y, va.z, va.w, vb.x, vb.y, vb.z, vb.w};
            float w[8] = {gm * wa.x, gm * wa.y, gm * wa.z, gm * wa.w,
                          gm * wb.x, gm * wb.y, gm * wb.z, gm * wb.w};
            #pragma unroll
            for (int i = 0; i < 8; ++i)
                #pragma unroll
                for (int j = 0; j < 8; ++j) acc[i][j] += v[i] * w[j];
        }
    }
    float* Gb = Gmat + ((size_t)((blockIdx.x & 3) * BB + b)) * DD * DD;
    #pragma unroll
    for (int i = 0; i < 8; ++i)
        #pragma unroll
        for (int j = 0; j < 8; ++j)
            atomicAdd(&Gb[(ty * 8 + i) * DD + tx * 8 + j], acc[i][j]);
}

// ---------------- final = raw + scale * raw @ G_b ----------------
__global__ __launch_bounds__(256) void k_final(
    const float* __restrict__ raw, const float* __restrict__ Gmat,
    const float* __restrict__ ti, float* __restrict__ out) {
    __shared__ float Gl[DD * DD];
    __shared__ float rawl[32 * DD];
    const int tid = threadIdx.x;
    const int b = blockIdx.y;
    const int s0 = blockIdx.x * 32;
    const float4* G0 = (const float4*)(Gmat + ((size_t)(0 * BB + b)) * DD * DD);
    const float4* G1 = (const float4*)(Gmat + ((size_t)(1 * BB + b)) * DD * DD);
    const float4* G2 = (const float4*)(Gmat + ((size_t)(2 * BB + b)) * DD * DD);
    const float4* G3 = (const float4*)(Gmat + ((size_t)(3 * BB + b)) * DD * DD);
    #pragma unroll
    for (int i = 0; i < 16; ++i) {
        int idx = tid + i * 256;
        float4 a = G0[idx], c = G1[idx], d = G2[idx], e = G3[idx];
        ((float4*)Gl)[idx] = make_float4(a.x + c.x + d.x + e.x, a.y + c.y + d.y + e.y,
                                         a.z + c.z + d.z + e.z, a.w + c.w + d.w + e.w);
    }
    const float4* rv = (const float4*)(raw + ((size_t)b * SS + s0) * DD);
    #pragma unroll
    for (int i = 0; i < 4; ++i) ((float4*)rawl)[tid + i * 256] = rv[tid + i * 256];
    __syncthreads();
    float tib = ti[b];
    float scale = (tib > 0.01f) ? 0.5f / (tib + 1e-5f) : 0.0f;
    const int dq = tid & 31;
    const int sg = tid >> 5;
    const float4* Gl4 = (const float4*)Gl;
    #pragma unroll 1
    for (int t = 0; t < 4; ++t) {
        int s = sg + t * 8;
        float4 acc = make_float4(0.f, 0.f, 0.f, 0.f);
        #pragma unroll
        for (int k = 0; k < DD; ++k) {
            float r = rawl[s * DD + k];
            float4 gv = Gl4[k * 32 + dq];
            acc.x += r * gv.x; acc.y += r * gv.y;
            acc.z += r * gv.z; acc.w += r * gv.w;
        }
        float4 rw = ((const float4*)rawl)[s * 32 + dq];
        float4 o = make_float4(rw.x + scale * acc.x, rw.y + scale * acc.y,
                               rw.z + scale * acc.z, rw.w + scale * acc.w);
        ((float4*)(out + ((size_t)b * SS + s0) * DD))[s * 32 + dq] = o;
    }
}

extern "C" void kernel_launch(void* const* d_in, const int* in_sizes, int n_in,
                              void* d_out, int out_size, void* d_ws, size_t ws_size,
                              hipStream_t stream) {
    const float* x   = (const float*)d_in[0];
    const float* mem = (const float*)d_in[1];
    const float* W1  = (const float*)d_in[2];
    const float* b1  = (const float*)d_in[3];
    const float* lg  = (const float*)d_in[4];
    const float* lb  = (const float*)d_in[5];
    const float* W2  = (const float*)d_in[6];
    const float* b2  = (const float*)d_in[7];
    float* out = (float*)d_out;

    float* wsf = (float*)d_ws;
    size_t off = 0;
    unsigned short* mnb = (unsigned short*)(wsf + off); off += (size_t)M_PAD * 64;
    float* norm_sq = wsf + off;                         off += M_PAD;
    unsigned short* xnb = (unsigned short*)(wsf + off); off += (size_t)BB * SS * 64;
    float* raw = wsf + off;                             off += (size_t)BB * SS * DD;
    float* cw  = wsf + off;                             off += (size_t)BB * M_PAD;
    float* g   = wsf + off;                             off += (size_t)BB * M_PAD;
    float* Gmat = wsf + off;                            off += (size_t)4 * BB * DD * DD;
    float* ti  = wsf + off;                             off += BB;

    k_init<<<dim3(1024), 256, 0, stream>>>(Gmat, ti);
    k_prep_mem<<<dim3(M_PAD / 4), 256, 0, stream>>>(mem, mnb, norm_sq);
    k_mlp<<<dim3(64), 256, 0, stream>>>(x, W1, b1, lg, lb, W2, b2, xnb, raw);
    k_cw<<<dim3(M_PAD / 64, BB), 256, 0, stream>>>(xnb, mnb, cw);
    k_gate<<<dim3((M_TOT + 255) / 256, BB), 256, 0, stream>>>(cw, norm_sq, g, ti);
    k_gmat<<<dim3(64, BB), 256, 0, stream>>>(mem, g, Gmat);
    k_final<<<dim3(SS / 32, BB), 256, 0, stream>>>(raw, Gmat, ti, out);
}

// Round 3
// 240.836 us; speedup vs baseline: 5.0149x; 1.3763x over previous
//
#include <hip/hip_runtime.h>

#define DD 128
#define SS 1024
#define BB 4
#define M_TOT 20000
#define M_PAD 20224   // 79*256

typedef __bf16 bf16x8 __attribute__((ext_vector_type(8)));
typedef float f32x16 __attribute__((ext_vector_type(16)));

__device__ __forceinline__ unsigned short f2bf(float f) {
    unsigned int u = __float_as_uint(f);
    u += 0x7FFFu + ((u >> 16) & 1u);
    return (unsigned short)(u >> 16);
}

// ---------------- init: zero G copies and ti ----------------
__global__ void k_init(float* __restrict__ Gmat, float* __restrict__ ti) {
    int idx = blockIdx.x * 256 + threadIdx.x;
    if (idx < 4 * BB * DD * DD) Gmat[idx] = 0.0f;
    if (idx < BB) ti[idx] = 0.0f;
}

// ---------------- prep: normalized mem rows (bf16) + norm_sq, padded ----------------
__global__ __launch_bounds__(256) void k_prep_mem(const float* __restrict__ mem,
                                                  unsigned short* __restrict__ mnb,
                                                  float* __restrict__ norm_sq) {
    int wv = threadIdx.x >> 6;
    int lane = threadIdx.x & 63;
    int row = blockIdx.x * 4 + wv;
    float2 v = make_float2(0.f, 0.f);
    if (row < M_TOT) v = *(const float2*)(mem + (size_t)row * DD + lane * 2);
    float ss = v.x * v.x + v.y * v.y;
    #pragma unroll
    for (int off = 1; off < 64; off <<= 1) ss += __shfl_xor(ss, off);
    float rs = rsqrtf(ss + 1e-12f);
    ushort2 o;
    o.x = f2bf(v.x * rs);
    o.y = f2bf(v.y * rs);
    *(ushort2*)(mnb + (size_t)row * DD + lane * 2) = o;
    if (lane == 0) norm_sq[row] = ss;
}

// ---------------- MLP (Linear->LN->ReLU->Linear) + xnb (bf16 normalized x) ----------------
// 256 threads: lane = token (64/block), wave = e-dim slice of 32.
__global__ __launch_bounds__(256) void k_mlp(
    const float* __restrict__ x, const float* __restrict__ W1,
    const float* __restrict__ b1, const float* __restrict__ ln_g,
    const float* __restrict__ ln_b, const float* __restrict__ W2,
    const float* __restrict__ b2, unsigned short* __restrict__ xnb,
    float* __restrict__ raw) {
    __shared__ float4 xl[64 * 33];
    __shared__ float4 hl[64 * 33];
    __shared__ float reds[4][64];
    __shared__ float redq[4][64];
    const int tid = threadIdx.x, lane = tid & 63, wv = tid >> 6;
    const int tok0 = blockIdx.x * 64;

    const float4* xv = (const float4*)x + (size_t)tok0 * 32;
    #pragma unroll
    for (int i = 0; i < 8; ++i) {
        int idx = tid + i * 256, r = idx >> 5, c = idx & 31;
        xl[r * 33 + c] = xv[idx];
    }
    __syncthreads();

    const float4* W1v = (const float4*)W1;
    float4 hreg[8];
    float hs = 0.f, hq = 0.f;
    #pragma unroll 1
    for (int e4 = 0; e4 < 8; ++e4) {
        int e = wv * 32 + e4 * 4;
        float a0 = b1[e], a1 = b1[e + 1], a2 = b1[e + 2], a3 = b1[e + 3];
        #pragma unroll
        for (int k4 = 0; k4 < 32; ++k4) {
            float4 xr = xl[lane * 33 + k4];
            float4 w0 = W1v[(size_t)(e + 0) * 32 + k4];
            float4 w1 = W1v[(size_t)(e + 1) * 32 + k4];
            float4 w2 = W1v[(size_t)(e + 2) * 32 + k4];
            float4 w3 = W1v[(size_t)(e + 3) * 32 + k4];
            a0 += xr.x * w0.x + xr.y * w0.y + xr.z * w0.z + xr.w * w0.w;
            a1 += xr.x * w1.x + xr.y * w1.y + xr.z * w1.z + xr.w * w1.w;
            a2 += xr.x * w2.x + xr.y * w2.y + xr.z * w2.z + xr.w * w2.w;
            a3 += xr.x * w3.x + xr.y * w3.y + xr.z * w3.z + xr.w * w3.w;
        }
        hreg[e4] = make_float4(a0, a1, a2, a3);
        hs += a0 + a1 + a2 + a3;
        hq += a0 * a0 + a1 * a1 + a2 * a2 + a3 * a3;
    }
    reds[wv][lane] = hs;
    redq[wv][lane] = hq;
    __syncthreads();
    float S = reds[0][lane] + reds[1][lane] + reds[2][lane] + reds[3][lane];
    float Q = redq[0][lane] + redq[1][lane] + redq[2][lane] + redq[3][lane];
    float mu = S * (1.f / 128.f);
    float rstd = rsqrtf(Q * (1.f / 128.f) - mu * mu + 1e-5f);

    // feats = relu(LN(h)) -> hl
    #pragma unroll
    for (int e4 = 0; e4 < 8; ++e4) {
        float4 hv = hreg[e4];
        float4 gv = ((const float4*)ln_g)[wv * 8 + e4];
        float4 bv = ((const float4*)ln_b)[wv * 8 + e4];
        hv.x = fmaxf((hv.x - mu) * rstd * gv.x + bv.x, 0.f);
        hv.y = fmaxf((hv.y - mu) * rstd * gv.y + bv.y, 0.f);
        hv.z = fmaxf((hv.z - mu) * rstd * gv.z + bv.z, 0.f);
        hv.w = fmaxf((hv.w - mu) * rstd * gv.w + bv.w, 0.f);
        hl[lane * 33 + wv * 8 + e4] = hv;
    }

    // xn: partial sum of squares over this wave's 32-dim slice
    float xq = 0.f;
    #pragma unroll
    for (int j = 0; j < 8; ++j) {
        float4 v = xl[lane * 33 + wv * 8 + j];
        xq += v.x * v.x + v.y * v.y + v.z * v.z + v.w * v.w;
    }
    __syncthreads();   // all reads of reds/redq done
    reds[wv][lane] = xq;
    __syncthreads();
    float XQ = reds[0][lane] + reds[1][lane] + reds[2][lane] + reds[3][lane];
    float xrs = rsqrtf(XQ + 1e-12f);
    #pragma unroll
    for (int j = 0; j < 8; ++j) {
        float4 v = xl[lane * 33 + wv * 8 + j];
        ushort4 o;
        o.x = f2bf(v.x * xrs); o.y = f2bf(v.y * xrs);
        o.z = f2bf(v.z * xrs); o.w = f2bf(v.w * xrs);
        *(ushort4*)(xnb + ((size_t)(tok0 + lane)) * DD + wv * 32 + j * 4) = o;
    }
    // hl fully written by all waves before the barrier above -> safe to read

    const float4* W2v = (const float4*)W2;
    #pragma unroll 1
    for (int e4 = 0; e4 < 8; ++e4) {
        int e = wv * 32 + e4 * 4;
        float a0 = b2[e], a1 = b2[e + 1], a2 = b2[e + 2], a3 = b2[e + 3];
        #pragma unroll
        for (int k4 = 0; k4 < 32; ++k4) {
            float4 fr = hl[lane * 33 + k4];
            float4 w0 = W2v[(size_t)(e + 0) * 32 + k4];
            float4 w1 = W2v[(size_t)(e + 1) * 32 + k4];
            float4 w2 = W2v[(size_t)(e + 2) * 32 + k4];
            float4 w3 = W2v[(size_t)(e + 3) * 32 + k4];
            a0 += fr.x * w0.x + fr.y * w0.y + fr.z * w0.z + fr.w * w0.w;
            a1 += fr.x * w1.x + fr.y * w1.y + fr.z * w1.z + fr.w * w1.w;
            a2 += fr.x * w2.x + fr.y * w2.y + fr.z * w2.z + fr.w * w2.w;
            a3 += fr.x * w3.x + fr.y * w3.y + fr.z * w3.z + fr.w * w3.w;
        }
        *(float4*)(raw + ((size_t)(tok0 + lane)) * DD + wv * 32 + e4 * 4) =
            make_float4(a0, a1, a2, a3);
    }
}

// ---------------- cw[b,m] = sum_s (sim>0.1 ? sim : 0) via bf16 MFMA ----------------
__global__ __launch_bounds__(256) void k_cw(
    const unsigned short* __restrict__ xnb, const unsigned short* __restrict__ mnb,
    float* __restrict__ cw) {
    __shared__ float red[4][64];
    const int tid = threadIdx.x;
    const int lane = tid & 63, wv = tid >> 6;
    const int col = lane & 31, kh = lane >> 5;
    const int b = blockIdx.y;
    const int m0 = blockIdx.x * 64;

    bf16x8 Bf[2][8];
    const unsigned short* mp = mnb + (size_t)(m0 + col) * DD + kh * 8;
    #pragma unroll
    for (int ct = 0; ct < 2; ++ct)
        #pragma unroll
        for (int kk = 0; kk < 8; ++kk)
            Bf[ct][kk] = *(const bf16x8*)(mp + (size_t)ct * 32 * DD + kk * 16);

    float cw0 = 0.f, cw1 = 0.f;
    const unsigned short* xp = xnb + ((size_t)b * SS + wv * 256 + col) * DD + kh * 8;

    #pragma unroll 1
    for (int st = 0; st < 8; ++st) {
        bf16x8 Af[8];
        #pragma unroll
        for (int kk = 0; kk < 8; ++kk)
            Af[kk] = *(const bf16x8*)(xp + (size_t)st * 32 * DD + kk * 16);
        f32x16 a0, a1;
        #pragma unroll
        for (int r = 0; r < 16; ++r) { a0[r] = 0.f; a1[r] = 0.f; }
        #pragma unroll
        for (int kk = 0; kk < 8; ++kk) {
            a0 = __builtin_amdgcn_mfma_f32_32x32x16_bf16(Af[kk], Bf[0][kk], a0, 0, 0, 0);
            a1 = __builtin_amdgcn_mfma_f32_32x32x16_bf16(Af[kk], Bf[1][kk], a1, 0, 0, 0);
        }
        #pragma unroll
        for (int r = 0; r < 16; ++r) {
            float v0 = a0[r], v1 = a1[r];
            cw0 += v0 > 0.1f ? v0 : 0.f;
            cw1 += v1 > 0.1f ? v1 : 0.f;
        }
    }
    cw0 += __shfl_xor(cw0, 32);
    cw1 += __shfl_xor(cw1, 32);
    if (lane < 32) { red[wv][col] = cw0; red[wv][col + 32] = cw1; }
    __syncthreads();
    if (tid < 64)
        cw[(size_t)b * M_PAD + m0 + tid] =
            red[0][tid] + red[1][tid] + red[2][tid] + red[3][tid];
}

// ---------------- gates: g = eff/safe_ns, ti = sum eff ----------------
__global__ __launch_bounds__(256) void k_gate(
    const float* __restrict__ cw, const float* __restrict__ norm_sq,
    float* __restrict__ g, float* __restrict__ ti) {
    const int b = blockIdx.y;
    const int idx = blockIdx.x * 256 + threadIdx.x;
    float e = 0.0f;
    if (idx < M_TOT) {
        float c = cw[(size_t)b * M_PAD + idx];
        float ns = norm_sq[idx];
        bool act = (c > 0.01f) && (ns > 1e-6f);
        e = act ? c : 0.0f;
        float sns = (ns > 1e-6f) ? ns : 1.0f;
        g[(size_t)b * M_PAD + idx] = e / sns;
    }
    __shared__ float rbuf[4];
    float t = e;
    #pragma unroll
    for (int off = 1; off < 64; off <<= 1) t += __shfl_xor(t, off);
    if ((threadIdx.x & 63) == 0) rbuf[threadIdx.x >> 6] = t;
    __syncthreads();
    if (threadIdx.x == 0) atomicAdd(&ti[b], rbuf[0] + rbuf[1] + rbuf[2] + rbuf[3]);
}

// ---------------- G_b = sum_m g[b,m] * mem[m] mem[m]^T ----------------
// grid (32 m-chunks, 4 row-tiles, BB) = 512 blocks. Each block: 32x128 slice
// of G over 625 m. g-scale folded into LDS staging (srows). 4x4 reg tiles.
// Atomic traffic: 512*4096*8B ~ 17 MB (was 134 MB).
#define GM_NCH 32
#define GM_CHUNK 625
__global__ __launch_bounds__(256) void k_gmat(
    const float* __restrict__ mem, const float* __restrict__ g,
    float* __restrict__ Gmat) {
    __shared__ float4 rows[16 * 33];
    __shared__ float4 srows[16 * 33];
    const int tid = threadIdx.x;
    const int tx = tid & 31;   // col group: cols tx*4..tx*4+3
    const int ty = tid >> 5;   // row group: rows rt*32 + ty*4..+3
    const int b = blockIdx.z;
    const int rt = blockIdx.y;
    const int m0 = blockIdx.x * GM_CHUNK;

    float acc[4][4];
    #pragma unroll
    for (int i = 0; i < 4; ++i)
        #pragma unroll
        for (int j = 0; j < 4; ++j) acc[i][j] = 0.0f;

    #pragma unroll 1
    for (int mt = 0; mt < GM_CHUNK; mt += 16) {
        const int mb = m0 + mt;
        __syncthreads();
        #pragma unroll
        for (int i = 0; i < 2; ++i) {
            int idx = tid + i * 256;
            int r = idx >> 5, c = idx & 31;
            int m = mb + r;
            float4 v = make_float4(0.f, 0.f, 0.f, 0.f);
            float gm = 0.f;
            if (m < M_TOT) {
                v = ((const float4*)mem)[(size_t)m * 32 + c];
                gm = g[(size_t)b * M_PAD + m];   // wave-uniform scalar load
            }
            rows[r * 33 + c] = v;
            srows[r * 33 + c] = make_float4(v.x * gm, v.y * gm, v.z * gm, v.w * gm);
        }
        __syncthreads();
        #pragma unroll
        for (int r = 0; r < 16; ++r) {
            float4 v = rows[r * 33 + rt * 8 + ty];   // 2-way broadcast read
            float4 w = srows[r * 33 + tx];           // stride-1, conflict-free
            acc[0][0] += v.x * w.x; acc[0][1] += v.x * w.y;
            acc[0][2] += v.x * w.z; acc[0][3] += v.x * w.w;
            acc[1][0] += v.y * w.x; acc[1][1] += v.y * w.y;
            acc[1][2] += v.y * w.z; acc[1][3] += v.y * w.w;
            acc[2][0] += v.z * w.x; acc[2][1] += v.z * w.y;
            acc[2][2] += v.z * w.z; acc[2][3] += v.z * w.w;
            acc[3][0] += v.w * w.x; acc[3][1] += v.w * w.y;
            acc[3][2] += v.w * w.z; acc[3][3] += v.w * w.w;
        }
    }
    float* Gb = Gmat + (size_t)((blockIdx.x & 3) * BB + b) * DD * DD;
    const int row0 = rt * 32 + ty * 4;
    #pragma unroll
    for (int i = 0; i < 4; ++i)
        #pragma unroll
        for (int j = 0; j < 4; ++j)
            atomicAdd(&Gb[(row0 + i) * DD + tx * 4 + j], acc[i][j]);
}

// ---------------- final = raw + scale * raw @ G_b ----------------
__global__ __launch_bounds__(256) void k_final(
    const float* __restrict__ raw, const float* __restrict__ Gmat,
    const float* __restrict__ ti, float* __restrict__ out) {
    __shared__ float Gl[DD * DD];
    __shared__ float rawl[32 * DD];
    const int tid = threadIdx.x;
    const int b = blockIdx.y;
    const int s0 = blockIdx.x * 32;
    const float4* G0 = (const float4*)(Gmat + ((size_t)(0 * BB + b)) * DD * DD);
    const float4* G1 = (const float4*)(Gmat + ((size_t)(1 * BB + b)) * DD * DD);
    const float4* G2 = (const float4*)(Gmat + ((size_t)(2 * BB + b)) * DD * DD);
    const float4* G3 = (const float4*)(Gmat + ((size_t)(3 * BB + b)) * DD * DD);
    #pragma unroll
    for (int i = 0; i < 16; ++i) {
        int idx = tid + i * 256;
        float4 a = G0[idx], c = G1[idx], d = G2[idx], e = G3[idx];
        ((float4*)Gl)[idx] = make_float4(a.x + c.x + d.x + e.x, a.y + c.y + d.y + e.y,
                                         a.z + c.z + d.z + e.z, a.w + c.w + d.w + e.w);
    }
    const float4* rv = (const float4*)(raw + ((size_t)b * SS + s0) * DD);
    #pragma unroll
    for (int i = 0; i < 4; ++i) ((float4*)rawl)[tid + i * 256] = rv[tid + i * 256];
    __syncthreads();
    float tib = ti[b];
    float scale = (tib > 0.01f) ? 0.5f / (tib + 1e-5f) : 0.0f;
    const int dq = tid & 31;
    const int sg = tid >> 5;
    const float4* Gl4 = (const float4*)Gl;
    #pragma unroll 1
    for (int t = 0; t < 4; ++t) {
        int s = sg + t * 8;
        float4 acc = make_float4(0.f, 0.f, 0.f, 0.f);
        #pragma unroll
        for (int k = 0; k < DD; ++k) {
            float r = rawl[s * DD + k];
            float4 gv = Gl4[k * 32 + dq];
            acc.x += r * gv.x; acc.y += r * gv.y;
            acc.z += r * gv.z; acc.w += r * gv.w;
        }
        float4 rw = ((const float4*)rawl)[s * 32 + dq];
        float4 o = make_float4(rw.x + scale * acc.x, rw.y + scale * acc.y,
                               rw.z + scale * acc.z, rw.w + scale * acc.w);
        ((float4*)(out + ((size_t)b * SS + s0) * DD))[s * 32 + dq] = o;
    }
}

extern "C" void kernel_launch(void* const* d_in, const int* in_sizes, int n_in,
                              void* d_out, int out_size, void* d_ws, size_t ws_size,
                              hipStream_t stream) {
    const float* x   = (const float*)d_in[0];
    const float* mem = (const float*)d_in[1];
    const float* W1  = (const float*)d_in[2];
    const float* b1  = (const float*)d_in[3];
    const float* lg  = (const float*)d_in[4];
    const float* lb  = (const float*)d_in[5];
    const float* W2  = (const float*)d_in[6];
    const float* b2  = (const float*)d_in[7];
    float* out = (float*)d_out;

    float* wsf = (float*)d_ws;
    size_t off = 0;
    unsigned short* mnb = (unsigned short*)(wsf + off); off += (size_t)M_PAD * 64;
    float* norm_sq = wsf + off;                         off += M_PAD;
    unsigned short* xnb = (unsigned short*)(wsf + off); off += (size_t)BB * SS * 64;
    float* raw = wsf + off;                             off += (size_t)BB * SS * DD;
    float* cw  = wsf + off;                             off += (size_t)BB * M_PAD;
    float* g   = wsf + off;                             off += (size_t)BB * M_PAD;
    float* Gmat = wsf + off;                            off += (size_t)4 * BB * DD * DD;
    float* ti  = wsf + off;                             off += BB;

    k_init<<<dim3(1024), 256, 0, stream>>>(Gmat, ti);
    k_prep_mem<<<dim3(M_PAD / 4), 256, 0, stream>>>(mem, mnb, norm_sq);
    k_mlp<<<dim3(64), 256, 0, stream>>>(x, W1, b1, lg, lb, W2, b2, xnb, raw);
    k_cw<<<dim3(M_PAD / 64, BB), 256, 0, stream>>>(xnb, mnb, cw);
    k_gate<<<dim3((M_TOT + 255) / 256, BB), 256, 0, stream>>>(cw, norm_sq, g, ti);
    k_gmat<<<dim3(GM_NCH, 4, BB), 256, 0, stream>>>(mem, g, Gmat);
    k_final<<<dim3(SS / 32, BB), 256, 0, stream>>>(raw, Gmat, ti, out);
}

// Round 4
// 156.997 us; speedup vs baseline: 7.6930x; 1.5340x over previous
//
#include <hip/hip_runtime.h>

#define DD 128
#define SS 1024
#define BB 4
#define M_TOT 20000
#define M_PAD 20224   // 316*64

typedef __bf16 bf16x8 __attribute__((ext_vector_type(8)));
typedef unsigned short u16x8 __attribute__((ext_vector_type(8)));
typedef float f32x16 __attribute__((ext_vector_type(16)));

union BF8 { bf16x8 b; u16x8 u; };

__device__ __forceinline__ unsigned short f2bf(float f) {
    unsigned int u = __float_as_uint(f);
    u += 0x7FFFu + ((u >> 16) & 1u);
    return (unsigned short)(u >> 16);
}
__device__ __forceinline__ float bf2f(unsigned short h) {
    return __uint_as_float(((unsigned int)h) << 16);
}

// ---------------- prep: normalized mem rows (bf16) + norm_sq + ti=0 ----------------
__global__ __launch_bounds__(256) void k_prep_mem(const float* __restrict__ mem,
                                                  unsigned short* __restrict__ mnb,
                                                  float* __restrict__ norm_sq,
                                                  float* __restrict__ ti) {
    if (blockIdx.x == 0 && threadIdx.x < BB) ti[threadIdx.x] = 0.0f;
    int wv = threadIdx.x >> 6;
    int lane = threadIdx.x & 63;
    int row = blockIdx.x * 4 + wv;
    float2 v = make_float2(0.f, 0.f);
    if (row < M_TOT) v = *(const float2*)(mem + (size_t)row * DD + lane * 2);
    float ss = v.x * v.x + v.y * v.y;
    #pragma unroll
    for (int off = 1; off < 64; off <<= 1) ss += __shfl_xor(ss, off);
    float rs = rsqrtf(ss + 1e-12f);
    ushort2 o;
    o.x = f2bf(v.x * rs);
    o.y = f2bf(v.y * rs);
    *(ushort2*)(mnb + (size_t)row * DD + lane * 2) = o;
    if (lane == 0) norm_sq[row] = ss;
}

// ---------------- fused MLP via MFMA + x-normalize ----------------
// 128 blocks x 256 thr. Block = 32 tokens. Wave wv owns col-tile ct=wv (32 e).
// GEMM1 (x@W1^T+b1) -> in-reg LN+ReLU (cross-lane butterfly + LDS cross-wave
// stats) -> feats bf16 in LDS -> GEMM2 (feats@W2^T+b2) -> raw fp32.
// Also writes xnb = bf16(normalize(x)) (wave 0).
__global__ __launch_bounds__(256) void k_fmlp(
    const float* __restrict__ x, const float* __restrict__ W1,
    const float* __restrict__ b1, const float* __restrict__ ln_g,
    const float* __restrict__ ln_b, const float* __restrict__ W2,
    const float* __restrict__ b2, unsigned short* __restrict__ xnb,
    float* __restrict__ raw) {
    __shared__ unsigned short featsL[32 * 136];
    __shared__ float red[4][32][2];
    __shared__ float2 stats[32];
    const int tid = threadIdx.x, lane = tid & 63, wv = tid >> 6;
    const int col = lane & 31, hi = lane >> 5;
    const int t0 = blockIdx.x * 32;
    const int ct = wv;

    // ---- A-frags from x (fp32 -> bf16), plus fp32 sumsq for xn ----
    bf16x8 Af[8];
    float sq = 0.f;
    const float* xrow = x + (size_t)(t0 + col) * DD + hi * 8;
    #pragma unroll
    for (int kk = 0; kk < 8; ++kk) {
        float4 p = *(const float4*)(xrow + kk * 16);
        float4 q = *(const float4*)(xrow + kk * 16 + 4);
        BF8 t;
        t.u[0] = f2bf(p.x); t.u[1] = f2bf(p.y); t.u[2] = f2bf(p.z); t.u[3] = f2bf(p.w);
        t.u[4] = f2bf(q.x); t.u[5] = f2bf(q.y); t.u[6] = f2bf(q.z); t.u[7] = f2bf(q.w);
        Af[kk] = t.b;
        sq += p.x * p.x + p.y * p.y + p.z * p.z + p.w * p.w;
        sq += q.x * q.x + q.y * q.y + q.z * q.z + q.w * q.w;
    }
    sq += __shfl_xor(sq, 32);
    float xrs = rsqrtf(sq + 1e-12f);
    if (wv == 0) {
        unsigned short* xo = xnb + (size_t)(t0 + col) * DD + hi * 8;
        #pragma unroll
        for (int kk = 0; kk < 8; ++kk) {
            BF8 t; t.b = Af[kk];
            u16x8 o;
            #pragma unroll
            for (int j = 0; j < 8; ++j) o[j] = f2bf(bf2f(t.u[j]) * xrs);
            *(u16x8*)(xo + kk * 16) = o;
        }
    }

    // ---- GEMM1: h = x @ W1^T + b1 ----
    f32x16 acc;
    {
        float bv = b1[ct * 32 + col];
        #pragma unroll
        for (int r = 0; r < 16; ++r) acc[r] = bv;
    }
    const float* w1row = W1 + (size_t)(ct * 32 + col) * DD + hi * 8;
    #pragma unroll
    for (int kk = 0; kk < 8; ++kk) {
        float4 p = *(const float4*)(w1row + kk * 16);
        float4 q = *(const float4*)(w1row + kk * 16 + 4);
        BF8 t;
        t.u[0] = f2bf(p.x); t.u[1] = f2bf(p.y); t.u[2] = f2bf(p.z); t.u[3] = f2bf(p.w);
        t.u[4] = f2bf(q.x); t.u[5] = f2bf(q.y); t.u[6] = f2bf(q.z); t.u[7] = f2bf(q.w);
        acc = __builtin_amdgcn_mfma_f32_32x32x16_bf16(Af[kk], t.b, acc, 0, 0, 0);
    }

    // ---- LN stats: per-reg cross-lane butterfly, cross-wave via LDS ----
    float rs_[16], rq_[16];
    #pragma unroll
    for (int r = 0; r < 16; ++r) { float v = acc[r]; rs_[r] = v; rq_[r] = v * v; }
    #pragma unroll
    for (int off = 1; off < 32; off <<= 1) {
        #pragma unroll
        for (int r = 0; r < 16; ++r) {
            rs_[r] += __shfl_xor(rs_[r], off);
            rq_[r] += __shfl_xor(rq_[r], off);
        }
    }
    if (col == 0) {
        #pragma unroll
        for (int r = 0; r < 16; ++r) {
            int row = (r & 3) + 8 * (r >> 2) + 4 * hi;
            red[wv][row][0] = rs_[r];
            red[wv][row][1] = rq_[r];
        }
    }
    __syncthreads();
    if (tid < 32) {
        float S = red[0][tid][0] + red[1][tid][0] + red[2][tid][0] + red[3][tid][0];
        float Q = red[0][tid][1] + red[1][tid][1] + red[2][tid][1] + red[3][tid][1];
        float mu = S * (1.f / 128.f);
        float rstd = rsqrtf(Q * (1.f / 128.f) - mu * mu + 1e-5f);
        stats[tid] = make_float2(mu, rstd);
    }
    __syncthreads();

    // ---- feats = relu(LN(h)) -> LDS bf16 ----
    {
        float gv = ln_g[ct * 32 + col], bv = ln_b[ct * 32 + col];
        #pragma unroll
        for (int r = 0; r < 16; ++r) {
            int row = (r & 3) + 8 * (r >> 2) + 4 * hi;
            float2 st = stats[row];
            float v = fmaxf((acc[r] - st.x) * st.y * gv + bv, 0.f);
            featsL[row * 136 + ct * 32 + col] = f2bf(v);
        }
    }
    __syncthreads();

    // ---- GEMM2: raw = feats @ W2^T + b2 ----
    f32x16 a2;
    {
        float bv = b2[ct * 32 + col];
        #pragma unroll
        for (int r = 0; r < 16; ++r) a2[r] = bv;
    }
    const float* w2row = W2 + (size_t)(ct * 32 + col) * DD + hi * 8;
    #pragma unroll
    for (int kk = 0; kk < 8; ++kk) {
        bf16x8 Aq = *(const bf16x8*)&featsL[(lane & 31) * 136 + hi * 8 + kk * 16];
        float4 p = *(const float4*)(w2row + kk * 16);
        float4 q = *(const float4*)(w2row + kk * 16 + 4);
        BF8 t;
        t.u[0] = f2bf(p.x); t.u[1] = f2bf(p.y); t.u[2] = f2bf(p.z); t.u[3] = f2bf(p.w);
        t.u[4] = f2bf(q.x); t.u[5] = f2bf(q.y); t.u[6] = f2bf(q.z); t.u[7] = f2bf(q.w);
        a2 = __builtin_amdgcn_mfma_f32_32x32x16_bf16(Aq, t.b, a2, 0, 0, 0);
    }
    #pragma unroll
    for (int r = 0; r < 16; ++r) {
        int row = (r & 3) + 8 * (r >> 2) + 4 * hi;
        raw[(size_t)(t0 + row) * DD + ct * 32 + col] = a2[r];
    }
}

// ---------------- cw[b,m] = sum_s (sim>0.1 ? sim : 0) via bf16 MFMA ----------------
__global__ __launch_bounds__(256) void k_cw(
    const unsigned short* __restrict__ xnb, const unsigned short* __restrict__ mnb,
    float* __restrict__ cw) {
    __shared__ float red[4][64];
    const int tid = threadIdx.x;
    const int lane = tid & 63, wv = tid >> 6;
    const int col = lane & 31, kh = lane >> 5;
    const int b = blockIdx.y;
    const int m0 = blockIdx.x * 64;

    bf16x8 Bf[2][8];
    const unsigned short* mp = mnb + (size_t)(m0 + col) * DD + kh * 8;
    #pragma unroll
    for (int ct = 0; ct < 2; ++ct)
        #pragma unroll
        for (int kk = 0; kk < 8; ++kk)
            Bf[ct][kk] = *(const bf16x8*)(mp + (size_t)ct * 32 * DD + kk * 16);

    float cw0 = 0.f, cw1 = 0.f;
    const unsigned short* xp = xnb + ((size_t)b * SS + wv * 256 + col) * DD + kh * 8;

    #pragma unroll 1
    for (int st = 0; st < 8; ++st) {
        bf16x8 Af[8];
        #pragma unroll
        for (int kk = 0; kk < 8; ++kk)
            Af[kk] = *(const bf16x8*)(xp + (size_t)st * 32 * DD + kk * 16);
        f32x16 a0, a1;
        #pragma unroll
        for (int r = 0; r < 16; ++r) { a0[r] = 0.f; a1[r] = 0.f; }
        #pragma unroll
        for (int kk = 0; kk < 8; ++kk) {
            a0 = __builtin_amdgcn_mfma_f32_32x32x16_bf16(Af[kk], Bf[0][kk], a0, 0, 0, 0);
            a1 = __builtin_amdgcn_mfma_f32_32x32x16_bf16(Af[kk], Bf[1][kk], a1, 0, 0, 0);
        }
        #pragma unroll
        for (int r = 0; r < 16; ++r) {
            float v0 = a0[r], v1 = a1[r];
            cw0 += v0 > 0.1f ? v0 : 0.f;
            cw1 += v1 > 0.1f ? v1 : 0.f;
        }
    }
    cw0 += __shfl_xor(cw0, 32);
    cw1 += __shfl_xor(cw1, 32);
    if (lane < 32) { red[wv][col] = cw0; red[wv][col + 32] = cw1; }
    __syncthreads();
    if (tid < 64)
        cw[(size_t)b * M_PAD + m0 + tid] =
            red[0][tid] + red[1][tid] + red[2][tid] + red[3][tid];
}

// ---------------- gates: g = eff/safe_ns, ti = sum eff ----------------
__global__ __launch_bounds__(256) void k_gate(
    const float* __restrict__ cw, const float* __restrict__ norm_sq,
    float* __restrict__ g, float* __restrict__ ti) {
    const int b = blockIdx.y;
    const int idx = blockIdx.x * 256 + threadIdx.x;
    float e = 0.0f;
    if (idx < M_TOT) {
        float c = cw[(size_t)b * M_PAD + idx];
        float ns = norm_sq[idx];
        bool act = (c > 0.01f) && (ns > 1e-6f);
        e = act ? c : 0.0f;
        float sns = (ns > 1e-6f) ? ns : 1.0f;
        g[(size_t)b * M_PAD + idx] = e / sns;
    }
    __shared__ float rbuf[4];
    float t = e;
    #pragma unroll
    for (int off = 1; off < 64; off <<= 1) t += __shfl_xor(t, off);
    if ((threadIdx.x & 63) == 0) rbuf[threadIdx.x >> 6] = t;
    __syncthreads();
    if (threadIdx.x == 0) atomicAdd(&ti[b], rbuf[0] + rbuf[1] + rbuf[2] + rbuf[3]);
}

// ---------------- gmat stage 1: partial G over m-chunk, no atomics ----------------
// grid (nch, BB). 256 thr as 16x16; each thread an 8x8 tile of full 128x128 G.
// Inner: 64 FMA : 4 ds_read_b128.
__global__ __launch_bounds__(256) void k_gmat1(
    const float* __restrict__ mem, const float* __restrict__ g,
    float* __restrict__ pG, int CH16) {
    __shared__ float rows[16 * 132];
    __shared__ float srows[16 * 132];
    const int tid = threadIdx.x;
    const int tx = tid & 15, ty = tid >> 4;
    const int b = blockIdx.y;
    const int m0 = blockIdx.x * CH16;

    float acc[8][8];
    #pragma unroll
    for (int i = 0; i < 8; ++i)
        #pragma unroll
        for (int j = 0; j < 8; ++j) acc[i][j] = 0.0f;

    #pragma unroll 1
    for (int mt = 0; mt < CH16; mt += 16) {
        const int mb = m0 + mt;
        __syncthreads();
        #pragma unroll
        for (int i = 0; i < 2; ++i) {
            int idx = tid + i * 256;
            int r = idx >> 5, c = idx & 31;
            int m = mb + r;
            float4 v = make_float4(0.f, 0.f, 0.f, 0.f);
            float gm = 0.f;
            if (m < M_TOT) {
                v = ((const float4*)mem)[(size_t)m * 32 + c];
                gm = g[(size_t)b * M_PAD + m];
            }
            *(float4*)&rows[r * 132 + c * 4] = v;
            *(float4*)&srows[r * 132 + c * 4] =
                make_float4(v.x * gm, v.y * gm, v.z * gm, v.w * gm);
        }
        __syncthreads();
        #pragma unroll
        for (int r = 0; r < 16; ++r) {
            float4 va = *(const float4*)&rows[r * 132 + ty * 8];
            float4 vb = *(const float4*)&rows[r * 132 + ty * 8 + 4];
            float4 wa = *(const float4*)&srows[r * 132 + tx * 8];
            float4 wb = *(const float4*)&srows[r * 132 + tx * 8 + 4];
            float v[8] = {va.x, va.y, va.z, va.w, vb.x, vb.y, vb.z, vb.w};
            float w[8] = {wa.x, wa.y, wa.z, wa.w, wb.x, wb.y, wb.z, wb.w};
            #pragma unroll
            for (int i = 0; i < 8; ++i)
                #pragma unroll
                for (int j = 0; j < 8; ++j) acc[i][j] += v[i] * w[j];
        }
    }
    float* out = pG + (size_t)(blockIdx.x * BB + b) * (DD * DD);
    #pragma unroll
    for (int i = 0; i < 8; ++i) {
        *(float4*)&out[(ty * 8 + i) * DD + tx * 8] =
            make_float4(acc[i][0], acc[i][1], acc[i][2], acc[i][3]);
        *(float4*)&out[(ty * 8 + i) * DD + tx * 8 + 4] =
            make_float4(acc[i][4], acc[i][5], acc[i][6], acc[i][7]);
    }
}

// ---------------- gmat stage 2: reduce partials -> G ----------------
__global__ __launch_bounds__(256) void k_gmat2(const float* __restrict__ pG,
                                               float* __restrict__ G, int nch) {
    const int b = blockIdx.y;
    const int i = (blockIdx.x * 256 + threadIdx.x) * 4;
    float4 s = make_float4(0.f, 0.f, 0.f, 0.f);
    for (int c = 0; c < nch; ++c) {
        float4 p = *(const float4*)&pG[(size_t)(c * BB + b) * (DD * DD) + i];
        s.x += p.x; s.y += p.y; s.z += p.z; s.w += p.w;
    }
    *(float4*)&G[(size_t)b * (DD * DD) + i] = s;
}

// ---------------- final = raw + scale * raw @ G_b ----------------
__global__ __launch_bounds__(256) void k_final(
    const float* __restrict__ raw, const float* __restrict__ Gmat,
    const float* __restrict__ ti, float* __restrict__ out) {
    __shared__ float Gl[DD * DD];
    __shared__ float rawl[32 * DD];
    const int tid = threadIdx.x;
    const int b = blockIdx.y;
    const int s0 = blockIdx.x * 32;
    const float4* Gv = (const float4*)(Gmat + (size_t)b * DD * DD);
    #pragma unroll
    for (int i = 0; i < 16; ++i) ((float4*)Gl)[tid + i * 256] = Gv[tid + i * 256];
    const float4* rv = (const float4*)(raw + ((size_t)b * SS + s0) * DD);
    #pragma unroll
    for (int i = 0; i < 4; ++i) ((float4*)rawl)[tid + i * 256] = rv[tid + i * 256];
    __syncthreads();
    float tib = ti[b];
    float scale = (tib > 0.01f) ? 0.5f / (tib + 1e-5f) : 0.0f;
    const int dq = tid & 31;
    const int sg = tid >> 5;
    const float4* Gl4 = (const float4*)Gl;
    #pragma unroll 1
    for (int t = 0; t < 4; ++t) {
        int s = sg + t * 8;
        float4 acc = make_float4(0.f, 0.f, 0.f, 0.f);
        #pragma unroll
        for (int k = 0; k < DD; ++k) {
            float r = rawl[s * DD + k];
            float4 gv = Gl4[k * 32 + dq];
            acc.x += r * gv.x; acc.y += r * gv.y;
            acc.z += r * gv.z; acc.w += r * gv.w;
        }
        float4 rw = ((const float4*)rawl)[s * 32 + dq];
        float4 o = make_float4(rw.x + scale * acc.x, rw.y + scale * acc.y,
                               rw.z + scale * acc.z, rw.w + scale * acc.w);
        ((float4*)(out + ((size_t)b * SS + s0) * DD))[s * 32 + dq] = o;
    }
}

extern "C" void kernel_launch(void* const* d_in, const int* in_sizes, int n_in,
                              void* d_out, int out_size, void* d_ws, size_t ws_size,
                              hipStream_t stream) {
    const float* x   = (const float*)d_in[0];
    const float* mem = (const float*)d_in[1];
    const float* W1  = (const float*)d_in[2];
    const float* b1  = (const float*)d_in[3];
    const float* lg  = (const float*)d_in[4];
    const float* lb  = (const float*)d_in[5];
    const float* W2  = (const float*)d_in[6];
    const float* b2  = (const float*)d_in[7];
    float* out = (float*)d_out;

    float* wsf = (float*)d_ws;
    size_t off = 0;
    unsigned short* mnb = (unsigned short*)(wsf + off); off += (size_t)M_PAD * 64;
    float* norm_sq = wsf + off;                         off += M_PAD;
    unsigned short* xnb = (unsigned short*)(wsf + off); off += (size_t)BB * SS * 64;
    float* raw = wsf + off;                             off += (size_t)BB * SS * DD;
    float* cw  = wsf + off;                             off += (size_t)BB * M_PAD;
    float* g   = wsf + off;                             off += (size_t)BB * M_PAD;
    float* G   = wsf + off;                             off += (size_t)BB * DD * DD;
    float* ti  = wsf + off;                             off += BB;
    size_t base = off;
    // pick nch (m-chunk count) so partials fit in workspace
    int nch = 64;
    while (nch > 2 &&
           (base + (size_t)nch * BB * DD * DD) * sizeof(float) > ws_size)
        nch >>= 1;
    float* pG = wsf + base;
    int CH = (M_TOT + nch - 1) / nch;
    int CH16 = ((CH + 15) / 16) * 16;

    k_prep_mem<<<dim3(M_PAD / 4), 256, 0, stream>>>(mem, mnb, norm_sq, ti);
    k_fmlp<<<dim3(SS * BB / 32), 256, 0, stream>>>(x, W1, b1, lg, lb, W2, b2, xnb, raw);
    k_cw<<<dim3(M_PAD / 64, BB), 256, 0, stream>>>(xnb, mnb, cw);
    k_gate<<<dim3((M_TOT + 255) / 256, BB), 256, 0, stream>>>(cw, norm_sq, g, ti);
    k_gmat1<<<dim3(nch, BB), 256, 0, stream>>>(mem, g, pG, CH16);
    k_gmat2<<<dim3(DD * DD / 1024, BB), 256, 0, stream>>>(pG, G, nch);
    k_final<<<dim3(SS / 32, BB), 256, 0, stream>>>(raw, G, ti, out);
}

// Round 5
// 96.168 us; speedup vs baseline: 12.5590x; 1.6325x over previous
//
#include <hip/hip_runtime.h>

#define DD 128
#define SS 1024
#define BB 4
#define M_TOT 20000
#define M_PAD 20224   // 79*256

typedef __bf16 bf16x8 __attribute__((ext_vector_type(8)));
typedef unsigned short u16x8 __attribute__((ext_vector_type(8)));
typedef float f32x16 __attribute__((ext_vector_type(16)));

union BF8 { bf16x8 b; u16x8 u; };

__device__ __forceinline__ unsigned short f2bf(float f) {
    unsigned int u = __float_as_uint(f);
    u += 0x7FFFu + ((u >> 16) & 1u);
    return (unsigned short)(u >> 16);
}
__device__ __forceinline__ float bf2f(unsigned short h) {
    return __uint_as_float(((unsigned int)h) << 16);
}

// ---------------- prep: normalized mem rows (bf16) + norm_sq; zero ti & cw ----------------
__global__ __launch_bounds__(256) void k_prep_mem(const float* __restrict__ mem,
                                                  unsigned short* __restrict__ mnb,
                                                  float* __restrict__ norm_sq,
                                                  float* __restrict__ ti,
                                                  float* __restrict__ cw) {
    if (blockIdx.x == 0 && threadIdx.x < BB) ti[threadIdx.x] = 0.0f;
    if (blockIdx.x < BB * M_PAD / 256) cw[blockIdx.x * 256 + threadIdx.x] = 0.0f;
    int wv = threadIdx.x >> 6;
    int lane = threadIdx.x & 63;
    int row = blockIdx.x * 4 + wv;
    float2 v = make_float2(0.f, 0.f);
    if (row < M_TOT) v = *(const float2*)(mem + (size_t)row * DD + lane * 2);
    float ss = v.x * v.x + v.y * v.y;
    #pragma unroll
    for (int off = 1; off < 64; off <<= 1) ss += __shfl_xor(ss, off);
    float rs = rsqrtf(ss + 1e-12f);
    ushort2 o;
    o.x = f2bf(v.x * rs);
    o.y = f2bf(v.y * rs);
    *(ushort2*)(mnb + (size_t)row * DD + lane * 2) = o;
    if (lane == 0) norm_sq[row] = ss;
}

// ---------------- fused MLP via MFMA + x-normalize (unchanged) ----------------
__global__ __launch_bounds__(256) void k_fmlp(
    const float* __restrict__ x, const float* __restrict__ W1,
    const float* __restrict__ b1, const float* __restrict__ ln_g,
    const float* __restrict__ ln_b, const float* __restrict__ W2,
    const float* __restrict__ b2, unsigned short* __restrict__ xnb,
    float* __restrict__ raw) {
    __shared__ unsigned short featsL[32 * 136];
    __shared__ float red[4][32][2];
    __shared__ float2 stats[32];
    const int tid = threadIdx.x, lane = tid & 63, wv = tid >> 6;
    const int col = lane & 31, hi = lane >> 5;
    const int t0 = blockIdx.x * 32;
    const int ct = wv;

    bf16x8 Af[8];
    float sq = 0.f;
    const float* xrow = x + (size_t)(t0 + col) * DD + hi * 8;
    #pragma unroll
    for (int kk = 0; kk < 8; ++kk) {
        float4 p = *(const float4*)(xrow + kk * 16);
        float4 q = *(const float4*)(xrow + kk * 16 + 4);
        BF8 t;
        t.u[0] = f2bf(p.x); t.u[1] = f2bf(p.y); t.u[2] = f2bf(p.z); t.u[3] = f2bf(p.w);
        t.u[4] = f2bf(q.x); t.u[5] = f2bf(q.y); t.u[6] = f2bf(q.z); t.u[7] = f2bf(q.w);
        Af[kk] = t.b;
        sq += p.x * p.x + p.y * p.y + p.z * p.z + p.w * p.w;
        sq += q.x * q.x + q.y * q.y + q.z * q.z + q.w * q.w;
    }
    sq += __shfl_xor(sq, 32);
    float xrs = rsqrtf(sq + 1e-12f);
    if (wv == 0) {
        unsigned short* xo = xnb + (size_t)(t0 + col) * DD + hi * 8;
        #pragma unroll
        for (int kk = 0; kk < 8; ++kk) {
            BF8 t; t.b = Af[kk];
            u16x8 o;
            #pragma unroll
            for (int j = 0; j < 8; ++j) o[j] = f2bf(bf2f(t.u[j]) * xrs);
            *(u16x8*)(xo + kk * 16) = o;
        }
    }

    f32x16 acc;
    {
        float bv = b1[ct * 32 + col];
        #pragma unroll
        for (int r = 0; r < 16; ++r) acc[r] = bv;
    }
    const float* w1row = W1 + (size_t)(ct * 32 + col) * DD + hi * 8;
    #pragma unroll
    for (int kk = 0; kk < 8; ++kk) {
        float4 p = *(const float4*)(w1row + kk * 16);
        float4 q = *(const float4*)(w1row + kk * 16 + 4);
        BF8 t;
        t.u[0] = f2bf(p.x); t.u[1] = f2bf(p.y); t.u[2] = f2bf(p.z); t.u[3] = f2bf(p.w);
        t.u[4] = f2bf(q.x); t.u[5] = f2bf(q.y); t.u[6] = f2bf(q.z); t.u[7] = f2bf(q.w);
        acc = __builtin_amdgcn_mfma_f32_32x32x16_bf16(Af[kk], t.b, acc, 0, 0, 0);
    }

    float rs_[16], rq_[16];
    #pragma unroll
    for (int r = 0; r < 16; ++r) { float v = acc[r]; rs_[r] = v; rq_[r] = v * v; }
    #pragma unroll
    for (int off = 1; off < 32; off <<= 1) {
        #pragma unroll
        for (int r = 0; r < 16; ++r) {
            rs_[r] += __shfl_xor(rs_[r], off);
            rq_[r] += __shfl_xor(rq_[r], off);
        }
    }
    if (col == 0) {
        #pragma unroll
        for (int r = 0; r < 16; ++r) {
            int row = (r & 3) + 8 * (r >> 2) + 4 * hi;
            red[wv][row][0] = rs_[r];
            red[wv][row][1] = rq_[r];
        }
    }
    __syncthreads();
    if (tid < 32) {
        float S = red[0][tid][0] + red[1][tid][0] + red[2][tid][0] + red[3][tid][0];
        float Q = red[0][tid][1] + red[1][tid][1] + red[2][tid][1] + red[3][tid][1];
        float mu = S * (1.f / 128.f);
        float rstd = rsqrtf(Q * (1.f / 128.f) - mu * mu + 1e-5f);
        stats[tid] = make_float2(mu, rstd);
    }
    __syncthreads();

    {
        float gv = ln_g[ct * 32 + col], bv = ln_b[ct * 32 + col];
        #pragma unroll
        for (int r = 0; r < 16; ++r) {
            int row = (r & 3) + 8 * (r >> 2) + 4 * hi;
            float2 st = stats[row];
            float v = fmaxf((acc[r] - st.x) * st.y * gv + bv, 0.f);
            featsL[row * 136 + ct * 32 + col] = f2bf(v);
        }
    }
    __syncthreads();

    f32x16 a2;
    {
        float bv = b2[ct * 32 + col];
        #pragma unroll
        for (int r = 0; r < 16; ++r) a2[r] = bv;
    }
    const float* w2row = W2 + (size_t)(ct * 32 + col) * DD + hi * 8;
    #pragma unroll
    for (int kk = 0; kk < 8; ++kk) {
        bf16x8 Aq = *(const bf16x8*)&featsL[(lane & 31) * 136 + hi * 8 + kk * 16];
        float4 p = *(const float4*)(w2row + kk * 16);
        float4 q = *(const float4*)(w2row + kk * 16 + 4);
        BF8 t;
        t.u[0] = f2bf(p.x); t.u[1] = f2bf(p.y); t.u[2] = f2bf(p.z); t.u[3] = f2bf(p.w);
        t.u[4] = f2bf(q.x); t.u[5] = f2bf(q.y); t.u[6] = f2bf(q.z); t.u[7] = f2bf(q.w);
        a2 = __builtin_amdgcn_mfma_f32_32x32x16_bf16(Aq, t.b, a2, 0, 0, 0);
    }
    #pragma unroll
    for (int r = 0; r < 16; ++r) {
        int row = (r & 3) + 8 * (r >> 2) + 4 * hi;
        raw[(size_t)(t0 + row) * DD + ct * 32 + col] = a2[r];
    }
}

// ---------------- cw: LDS-staged A (xnb tile shared by 4 waves), B in regs ----------------
// grid (79 m-tiles, 2 s-halves, BB). Wave wv owns m sub-tile of 64 (2 col-tiles).
// Per iter: stage 32s x 128k bf16 swizzled -> 16 MFMA/wave -> threshold epilogue.
__global__ __launch_bounds__(256, 3) void k_cw(
    const unsigned short* __restrict__ xnb, const unsigned short* __restrict__ mnb,
    float* __restrict__ cw) {
    __shared__ unsigned short As[32 * 128];
    const int tid = threadIdx.x, lane = tid & 63, wv = tid >> 6;
    const int c = lane & 31, h = lane >> 5;
    const int b = blockIdx.z;
    const int mw = blockIdx.x * 256 + wv * 64;
    const int s_base = blockIdx.y * 512;

    bf16x8 Bf[2][8];
    #pragma unroll
    for (int ct = 0; ct < 2; ++ct)
        #pragma unroll
        for (int kk = 0; kk < 8; ++kk)
            Bf[ct][kk] = *(const bf16x8*)(mnb + (size_t)(mw + ct * 32 + c) * DD +
                                          kk * 16 + h * 8);

    float cw0 = 0.f, cw1 = 0.f;
    #pragma unroll 1
    for (int it = 0; it < 16; ++it) {
        const int st = s_base + it * 32;
        #pragma unroll
        for (int i = 0; i < 2; ++i) {
            int u = tid + i * 256;
            int row = u >> 4, k16 = u & 15;
            u16x8 v = *(const u16x8*)(xnb + ((size_t)b * SS + st + row) * DD + k16 * 8);
            *(u16x8*)&As[row * 128 + ((k16 * 8) ^ ((row & 15) << 3))] = v;
        }
        __syncthreads();
        f32x16 p0, p1;
        #pragma unroll
        for (int r = 0; r < 16; ++r) { p0[r] = 0.f; p1[r] = 0.f; }
        #pragma unroll
        for (int kk = 0; kk < 8; ++kk) {
            bf16x8 Afr = *(const bf16x8*)&As[c * 128 + ((kk * 16 + h * 8) ^ ((c & 15) << 3))];
            p0 = __builtin_amdgcn_mfma_f32_32x32x16_bf16(Afr, Bf[0][kk], p0, 0, 0, 0);
            p1 = __builtin_amdgcn_mfma_f32_32x32x16_bf16(Afr, Bf[1][kk], p1, 0, 0, 0);
        }
        __syncthreads();
        #pragma unroll
        for (int r = 0; r < 16; ++r) {
            float v0 = p0[r], v1 = p1[r];
            cw0 += v0 > 0.1f ? v0 : 0.f;
            cw1 += v1 > 0.1f ? v1 : 0.f;
        }
    }
    cw0 += __shfl_xor(cw0, 32);
    cw1 += __shfl_xor(cw1, 32);
    if (lane < 32) {
        atomicAdd(&cw[(size_t)b * M_PAD + mw + c], cw0);
        atomicAdd(&cw[(size_t)b * M_PAD + mw + 32 + c], cw1);
    }
}

// ---------------- gmat via MFMA: G_b = sum_m eff[b,m] * mn[m] mn[m]^T ----------------
// gate fused (eff from cw & norm_sq; ti atomicAdd). 256 blocks (64 chunks x BB),
// each block: full 128x128 G over 320 m; transpose-stage mnb into swizzled LDS.
#define GM_NCH 64
#define GM_CH 320
__global__ __launch_bounds__(256) void k_gmatm(
    const unsigned short* __restrict__ mnb, const float* __restrict__ cw,
    const float* __restrict__ norm_sq, float* __restrict__ ti,
    float* __restrict__ pG) {
    __shared__ unsigned short At[128 * 64];
    __shared__ unsigned short Bt[128 * 64];
    __shared__ float effL[GM_CH];
    __shared__ float rb[4];
    const int tid = threadIdx.x, lane = tid & 63, wv = tid >> 6;
    const int c = lane & 31, h = lane >> 5;
    const int b = blockIdx.y;
    const int m0 = blockIdx.x * GM_CH;

    // fused gate: eff + ti partial
    float tsum = 0.f;
    for (int idx = tid; idx < GM_CH; idx += 256) {
        int m = m0 + idx;
        float e = 0.f;
        if (m < M_TOT) {
            float cc = cw[(size_t)b * M_PAD + m];
            float ns = norm_sq[m];
            e = (cc > 0.01f && ns > 1e-6f) ? cc : 0.f;
        }
        effL[idx] = e;
        tsum += e;
    }
    #pragma unroll
    for (int off = 1; off < 64; off <<= 1) tsum += __shfl_xor(tsum, off);
    if (lane == 0) rb[wv] = tsum;
    __syncthreads();
    if (tid == 0) atomicAdd(&ti[b], rb[0] + rb[1] + rb[2] + rb[3]);

    f32x16 a0, a1, a2, a3;
    #pragma unroll
    for (int r = 0; r < 16; ++r) { a0[r] = 0.f; a1[r] = 0.f; a2[r] = 0.f; a3[r] = 0.f; }

    const int ml = tid & 63, dgrp = tid >> 6;
    #pragma unroll 1
    for (int t = 0; t < GM_CH / 64; ++t) {
        const int mt0 = m0 + t * 64;
        __syncthreads();   // prior mfma reads done
        const float em = effL[t * 64 + ml];
        const int m = mt0 + ml;
        const bool ok = m < M_TOT;
        const unsigned short* mrow = mnb + (size_t)m * DD;
        #pragma unroll 8
        for (int i = 0; i < 32; ++i) {
            int d = dgrp * 32 + i;
            unsigned short u = ok ? mrow[d] : (unsigned short)0;
            int us = d * 64 + (ml ^ ((d & 7) << 3));
            Bt[us] = u;
            At[us] = f2bf(bf2f(u) * em);
        }
        __syncthreads();
        #pragma unroll
        for (int kk = 0; kk < 4; ++kk) {
            int mo = kk * 16 + h * 8;
            bf16x8 Afr = *(const bf16x8*)&At[(wv * 32 + c) * 64 + (mo ^ ((c & 7) << 3))];
            bf16x8 B0 = *(const bf16x8*)&Bt[(0 * 32 + c) * 64 + (mo ^ ((c & 7) << 3))];
            bf16x8 B1 = *(const bf16x8*)&Bt[(1 * 32 + c) * 64 + (mo ^ ((c & 7) << 3))];
            bf16x8 B2 = *(const bf16x8*)&Bt[(2 * 32 + c) * 64 + (mo ^ ((c & 7) << 3))];
            bf16x8 B3 = *(const bf16x8*)&Bt[(3 * 32 + c) * 64 + (mo ^ ((c & 7) << 3))];
            a0 = __builtin_amdgcn_mfma_f32_32x32x16_bf16(Afr, B0, a0, 0, 0, 0);
            a1 = __builtin_amdgcn_mfma_f32_32x32x16_bf16(Afr, B1, a1, 0, 0, 0);
            a2 = __builtin_amdgcn_mfma_f32_32x32x16_bf16(Afr, B2, a2, 0, 0, 0);
            a3 = __builtin_amdgcn_mfma_f32_32x32x16_bf16(Afr, B3, a3, 0, 0, 0);
        }
    }
    float* o = pG + (size_t)(blockIdx.x * BB + b) * (DD * DD);
    #pragma unroll
    for (int r = 0; r < 16; ++r) {
        int rf = (r & 3) + 8 * (r >> 2) + 4 * h;
        o[(wv * 32 + rf) * DD + 0 * 32 + c] = a0[r];
        o[(wv * 32 + rf) * DD + 1 * 32 + c] = a1[r];
        o[(wv * 32 + rf) * DD + 2 * 32 + c] = a2[r];
        o[(wv * 32 + rf) * DD + 3 * 32 + c] = a3[r];
    }
}

// ---------------- gmat stage 2: reduce partials -> G ----------------
__global__ __launch_bounds__(256) void k_gmat2(const float* __restrict__ pG,
                                               float* __restrict__ G) {
    const int b = blockIdx.y;
    const int i = (blockIdx.x * 256 + threadIdx.x) * 4;
    float4 s = make_float4(0.f, 0.f, 0.f, 0.f);
    for (int c = 0; c < GM_NCH; ++c) {
        float4 p = *(const float4*)&pG[(size_t)(c * BB + b) * (DD * DD) + i];
        s.x += p.x; s.y += p.y; s.z += p.z; s.w += p.w;
    }
    *(float4*)&G[(size_t)b * (DD * DD) + i] = s;
}

// ---------------- final = raw + scale * raw @ G_b ----------------
__global__ __launch_bounds__(256) void k_final(
    const float* __restrict__ raw, const float* __restrict__ Gmat,
    const float* __restrict__ ti, float* __restrict__ out) {
    __shared__ float Gl[DD * DD];
    __shared__ float rawl[32 * DD];
    const int tid = threadIdx.x;
    const int b = blockIdx.y;
    const int s0 = blockIdx.x * 32;
    const float4* Gv = (const float4*)(Gmat + (size_t)b * DD * DD);
    #pragma unroll
    for (int i = 0; i < 16; ++i) ((float4*)Gl)[tid + i * 256] = Gv[tid + i * 256];
    const float4* rv = (const float4*)(raw + ((size_t)b * SS + s0) * DD);
    #pragma unroll
    for (int i = 0; i < 4; ++i) ((float4*)rawl)[tid + i * 256] = rv[tid + i * 256];
    __syncthreads();
    float tib = ti[b];
    float scale = (tib > 0.01f) ? 0.5f / (tib + 1e-5f) : 0.0f;
    const int dq = tid & 31;
    const int sg = tid >> 5;
    const float4* Gl4 = (const float4*)Gl;
    #pragma unroll 1
    for (int t = 0; t < 4; ++t) {
        int s = sg + t * 8;
        float4 acc = make_float4(0.f, 0.f, 0.f, 0.f);
        #pragma unroll
        for (int k = 0; k < DD; ++k) {
            float r = rawl[s * DD + k];
            float4 gv = Gl4[k * 32 + dq];
            acc.x += r * gv.x; acc.y += r * gv.y;
            acc.z += r * gv.z; acc.w += r * gv.w;
        }
        float4 rw = ((const float4*)rawl)[s * 32 + dq];
        float4 o = make_float4(rw.x + scale * acc.x, rw.y + scale * acc.y,
                               rw.z + scale * acc.z, rw.w + scale * acc.w);
        ((float4*)(out + ((size_t)b * SS + s0) * DD))[s * 32 + dq] = o;
    }
}

extern "C" void kernel_launch(void* const* d_in, const int* in_sizes, int n_in,
                              void* d_out, int out_size, void* d_ws, size_t ws_size,
                              hipStream_t stream) {
    const float* x   = (const float*)d_in[0];
    const float* mem = (const float*)d_in[1];
    const float* W1  = (const float*)d_in[2];
    const float* b1  = (const float*)d_in[3];
    const float* lg  = (const float*)d_in[4];
    const float* lb  = (const float*)d_in[5];
    const float* W2  = (const float*)d_in[6];
    const float* b2  = (const float*)d_in[7];
    float* out = (float*)d_out;

    float* wsf = (float*)d_ws;
    size_t off = 0;
    unsigned short* mnb = (unsigned short*)(wsf + off); off += (size_t)M_PAD * 64;
    float* norm_sq = wsf + off;                         off += M_PAD;
    unsigned short* xnb = (unsigned short*)(wsf + off); off += (size_t)BB * SS * 64;
    float* raw = wsf + off;                             off += (size_t)BB * SS * DD;
    float* cw  = wsf + off;                             off += (size_t)BB * M_PAD;
    float* G   = wsf + off;                             off += (size_t)BB * DD * DD;
    float* ti  = wsf + off;                             off += BB;
    float* pG  = wsf + off;                             off += (size_t)GM_NCH * BB * DD * DD;

    k_prep_mem<<<dim3(M_PAD / 4), 256, 0, stream>>>(mem, mnb, norm_sq, ti, cw);
    k_fmlp<<<dim3(SS * BB / 32), 256, 0, stream>>>(x, W1, b1, lg, lb, W2, b2, xnb, raw);
    k_cw<<<dim3(M_PAD / 256, 2, BB), 256, 0, stream>>>(xnb, mnb, cw);
    k_gmatm<<<dim3(GM_NCH, BB), 256, 0, stream>>>(mnb, cw, norm_sq, ti, pG);
    k_gmat2<<<dim3(DD * DD / 1024, BB), 256, 0, stream>>>(pG, G);
    k_final<<<dim3(SS / 32, BB), 256, 0, stream>>>(raw, G, ti, out);
}

// Round 6
// 92.573 us; speedup vs baseline: 13.0466x; 1.0388x over previous
//
#include <hip/hip_runtime.h>

#define DD 128
#define SS 1024
#define BB 4
#define M_TOT 20000
#define M_PAD 20224   // 79*256

typedef __bf16 bf16x8 __attribute__((ext_vector_type(8)));
typedef unsigned short u16x8 __attribute__((ext_vector_type(8)));
typedef float f32x16 __attribute__((ext_vector_type(16)));

union BF8 { bf16x8 b; u16x8 u; };

__device__ __forceinline__ unsigned short f2bf(float f) {
    unsigned int u = __float_as_uint(f);
    u += 0x7FFFu + ((u >> 16) & 1u);
    return (unsigned short)(u >> 16);
}
__device__ __forceinline__ float bf2f(unsigned short h) {
    return __uint_as_float(((unsigned int)h) << 16);
}

// ---------------- prep: mnb (bf16 normalized mem) + norm_sq; zero ti & cw;
// ---------------- convert W1,W2 -> bf16 (blocks 0..127) ----------------
__global__ __launch_bounds__(256) void k_prep_mem(const float* __restrict__ mem,
                                                  unsigned short* __restrict__ mnb,
                                                  float* __restrict__ norm_sq,
                                                  float* __restrict__ ti,
                                                  float* __restrict__ cw,
                                                  const float* __restrict__ W1,
                                                  const float* __restrict__ W2,
                                                  unsigned short* __restrict__ w1b,
                                                  unsigned short* __restrict__ w2b) {
    if (blockIdx.x == 0 && threadIdx.x < BB) ti[threadIdx.x] = 0.0f;
    if (blockIdx.x < BB * M_PAD / 256) cw[blockIdx.x * 256 + threadIdx.x] = 0.0f;
    if (blockIdx.x < 128) {
        int idx = blockIdx.x * 256 + threadIdx.x;   // 0..32767
        if (idx < DD * DD) w1b[idx] = f2bf(W1[idx]);
        else               w2b[idx - DD * DD] = f2bf(W2[idx - DD * DD]);
    }
    int wv = threadIdx.x >> 6;
    int lane = threadIdx.x & 63;
    int row = blockIdx.x * 4 + wv;
    float2 v = make_float2(0.f, 0.f);
    if (row < M_TOT) v = *(const float2*)(mem + (size_t)row * DD + lane * 2);
    float ss = v.x * v.x + v.y * v.y;
    #pragma unroll
    for (int off = 1; off < 64; off <<= 1) ss += __shfl_xor(ss, off);
    float rs = rsqrtf(ss + 1e-12f);
    ushort2 o;
    o.x = f2bf(v.x * rs);
    o.y = f2bf(v.y * rs);
    *(ushort2*)(mnb + (size_t)row * DD + lane * 2) = o;
    if (lane == 0) norm_sq[row] = ss;
}

// ---------------- fused MLP via MFMA + x-normalize (bf16 weights) ----------------
__global__ __launch_bounds__(256) void k_fmlp(
    const float* __restrict__ x, const unsigned short* __restrict__ w1b,
    const float* __restrict__ b1, const float* __restrict__ ln_g,
    const float* __restrict__ ln_b, const unsigned short* __restrict__ w2b,
    const float* __restrict__ b2, unsigned short* __restrict__ xnb,
    float* __restrict__ raw) {
    __shared__ unsigned short featsL[32 * 136];
    __shared__ float red[4][32][2];
    __shared__ float2 stats[32];
    const int tid = threadIdx.x, lane = tid & 63, wv = tid >> 6;
    const int col = lane & 31, hi = lane >> 5;
    const int t0 = blockIdx.x * 32;
    const int ct = wv;

    bf16x8 Af[8];
    float sq = 0.f;
    const float* xrow = x + (size_t)(t0 + col) * DD + hi * 8;
    #pragma unroll
    for (int kk = 0; kk < 8; ++kk) {
        float4 p = *(const float4*)(xrow + kk * 16);
        float4 q = *(const float4*)(xrow + kk * 16 + 4);
        BF8 t;
        t.u[0] = f2bf(p.x); t.u[1] = f2bf(p.y); t.u[2] = f2bf(p.z); t.u[3] = f2bf(p.w);
        t.u[4] = f2bf(q.x); t.u[5] = f2bf(q.y); t.u[6] = f2bf(q.z); t.u[7] = f2bf(q.w);
        Af[kk] = t.b;
        sq += p.x * p.x + p.y * p.y + p.z * p.z + p.w * p.w;
        sq += q.x * q.x + q.y * q.y + q.z * q.z + q.w * q.w;
    }
    sq += __shfl_xor(sq, 32);
    float xrs = rsqrtf(sq + 1e-12f);
    if (wv == 0) {
        unsigned short* xo = xnb + (size_t)(t0 + col) * DD + hi * 8;
        #pragma unroll
        for (int kk = 0; kk < 8; ++kk) {
            BF8 t; t.b = Af[kk];
            u16x8 o;
            #pragma unroll
            for (int j = 0; j < 8; ++j) o[j] = f2bf(bf2f(t.u[j]) * xrs);
            *(u16x8*)(xo + kk * 16) = o;
        }
    }

    f32x16 acc;
    {
        float bv = b1[ct * 32 + col];
        #pragma unroll
        for (int r = 0; r < 16; ++r) acc[r] = bv;
    }
    const unsigned short* w1row = w1b + (size_t)(ct * 32 + col) * DD + hi * 8;
    #pragma unroll
    for (int kk = 0; kk < 8; ++kk) {
        bf16x8 Bw = *(const bf16x8*)(w1row + kk * 16);
        acc = __builtin_amdgcn_mfma_f32_32x32x16_bf16(Af[kk], Bw, acc, 0, 0, 0);
    }

    float rs_[16], rq_[16];
    #pragma unroll
    for (int r = 0; r < 16; ++r) { float v = acc[r]; rs_[r] = v; rq_[r] = v * v; }
    #pragma unroll
    for (int off = 1; off < 32; off <<= 1) {
        #pragma unroll
        for (int r = 0; r < 16; ++r) {
            rs_[r] += __shfl_xor(rs_[r], off);
            rq_[r] += __shfl_xor(rq_[r], off);
        }
    }
    if (col == 0) {
        #pragma unroll
        for (int r = 0; r < 16; ++r) {
            int row = (r & 3) + 8 * (r >> 2) + 4 * hi;
            red[wv][row][0] = rs_[r];
            red[wv][row][1] = rq_[r];
        }
    }
    __syncthreads();
    if (tid < 32) {
        float S = red[0][tid][0] + red[1][tid][0] + red[2][tid][0] + red[3][tid][0];
        float Q = red[0][tid][1] + red[1][tid][1] + red[2][tid][1] + red[3][tid][1];
        float mu = S * (1.f / 128.f);
        float rstd = rsqrtf(Q * (1.f / 128.f) - mu * mu + 1e-5f);
        stats[tid] = make_float2(mu, rstd);
    }
    __syncthreads();

    {
        float gv = ln_g[ct * 32 + col], bv = ln_b[ct * 32 + col];
        #pragma unroll
        for (int r = 0; r < 16; ++r) {
            int row = (r & 3) + 8 * (r >> 2) + 4 * hi;
            float2 st = stats[row];
            float v = fmaxf((acc[r] - st.x) * st.y * gv + bv, 0.f);
            featsL[row * 136 + ct * 32 + col] = f2bf(v);
        }
    }
    __syncthreads();

    f32x16 a2;
    {
        float bv = b2[ct * 32 + col];
        #pragma unroll
        for (int r = 0; r < 16; ++r) a2[r] = bv;
    }
    const unsigned short* w2row = w2b + (size_t)(ct * 32 + col) * DD + hi * 8;
    #pragma unroll
    for (int kk = 0; kk < 8; ++kk) {
        bf16x8 Aq = *(const bf16x8*)&featsL[(lane & 31) * 136 + hi * 8 + kk * 16];
        bf16x8 Bw = *(const bf16x8*)(w2row + kk * 16);
        a2 = __builtin_amdgcn_mfma_f32_32x32x16_bf16(Aq, Bw, a2, 0, 0, 0);
    }
    #pragma unroll
    for (int r = 0; r < 16; ++r) {
        int row = (r & 3) + 8 * (r >> 2) + 4 * hi;
        raw[(size_t)(t0 + row) * DD + ct * 32 + col] = a2[r];
    }
}

// ---------------- cw: double-buffered LDS A-tile, B in regs ----------------
// grid (79 m-tiles, 2 s-halves, BB). Wave wv owns 64 m (2 col-tiles).
// One barrier/iter; next tile's global loads issued before the MFMA chain.
__global__ __launch_bounds__(256, 3) void k_cw(
    const unsigned short* __restrict__ xnb, const unsigned short* __restrict__ mnb,
    float* __restrict__ cw) {
    __shared__ unsigned short As[2][32 * 128];
    const int tid = threadIdx.x, lane = tid & 63, wv = tid >> 6;
    const int c = lane & 31, h = lane >> 5;
    const int b = blockIdx.z;
    const int mw = blockIdx.x * 256 + wv * 64;
    const int s_base = blockIdx.y * 512;

    const int srow = tid >> 4, sk16 = tid & 15;          // staging coords (i=0)
    const int soff = srow * 128 + ((sk16 * 8) ^ ((srow & 15) << 3));
    const int srow1 = (tid + 256) >> 4, sk161 = tid & 15;
    const int soff1 = srow1 * 128 + ((sk161 * 8) ^ ((srow1 & 15) << 3));
    const unsigned short* xbase = xnb + ((size_t)b * SS + s_base) * DD;

    bf16x8 Bf[2][8];
    #pragma unroll
    for (int ct = 0; ct < 2; ++ct)
        #pragma unroll
        for (int kk = 0; kk < 8; ++kk)
            Bf[ct][kk] = *(const bf16x8*)(mnb + (size_t)(mw + ct * 32 + c) * DD +
                                          kk * 16 + h * 8);

    // prologue: stage tile 0
    {
        u16x8 v0 = *(const u16x8*)(xbase + (size_t)srow * DD + sk16 * 8);
        u16x8 v1 = *(const u16x8*)(xbase + (size_t)srow1 * DD + sk161 * 8);
        *(u16x8*)&As[0][soff] = v0;
        *(u16x8*)&As[0][soff1] = v1;
    }

    float cw0 = 0.f, cw1 = 0.f;
    #pragma unroll 1
    for (int it = 0; it < 16; ++it) {
        __syncthreads();   // As[it&1] fully staged; prior reads of As[(it+1)&1] done
        u16x8 v0, v1;
        if (it < 15) {
            const unsigned short* nb = xbase + (size_t)(it + 1) * 32 * DD;
            v0 = *(const u16x8*)(nb + (size_t)srow * DD + sk16 * 8);
            v1 = *(const u16x8*)(nb + (size_t)srow1 * DD + sk161 * 8);
        }
        f32x16 p0, p1;
        #pragma unroll
        for (int r = 0; r < 16; ++r) { p0[r] = 0.f; p1[r] = 0.f; }
        const unsigned short* Ab = As[it & 1];
        #pragma unroll
        for (int kk = 0; kk < 8; ++kk) {
            bf16x8 Afr = *(const bf16x8*)&Ab[c * 128 + ((kk * 16 + h * 8) ^ ((c & 15) << 3))];
            p0 = __builtin_amdgcn_mfma_f32_32x32x16_bf16(Afr, Bf[0][kk], p0, 0, 0, 0);
            p1 = __builtin_amdgcn_mfma_f32_32x32x16_bf16(Afr, Bf[1][kk], p1, 0, 0, 0);
        }
        if (it < 15) {
            unsigned short* An = As[(it + 1) & 1];
            *(u16x8*)&An[soff] = v0;
            *(u16x8*)&An[soff1] = v1;
        }
        #pragma unroll
        for (int r = 0; r < 16; ++r) {
            float a = p0[r], bb = p1[r];
            cw0 += a > 0.1f ? a : 0.f;
            cw1 += bb > 0.1f ? bb : 0.f;
        }
    }
    cw0 += __shfl_xor(cw0, 32);
    cw1 += __shfl_xor(cw1, 32);
    if (lane < 32) {
        atomicAdd(&cw[(size_t)b * M_PAD + mw + c], cw0);
        atomicAdd(&cw[(size_t)b * M_PAD + mw + 32 + c], cw1);
    }
}

// ---------------- gmat via MFMA: G_b = sum_m eff[b,m] * mn[m] mn[m]^T ----------------
#define GM_NCH 64
#define GM_CH 320
__global__ __launch_bounds__(256) void k_gmatm(
    const unsigned short* __restrict__ mnb, const float* __restrict__ cw,
    const float* __restrict__ norm_sq, float* __restrict__ ti,
    float* __restrict__ pG) {
    __shared__ unsigned short At[128 * 64];
    __shared__ unsigned short Bt[128 * 64];
    __shared__ float effL[GM_CH];
    __shared__ float rb[4];
    const int tid = threadIdx.x, lane = tid & 63, wv = tid >> 6;
    const int c = lane & 31, h = lane >> 5;
    const int b = blockIdx.y;
    const int m0 = blockIdx.x * GM_CH;

    float tsum = 0.f;
    for (int idx = tid; idx < GM_CH; idx += 256) {
        int m = m0 + idx;
        float e = 0.f;
        if (m < M_TOT) {
            float cc = cw[(size_t)b * M_PAD + m];
            float ns = norm_sq[m];
            e = (cc > 0.01f && ns > 1e-6f) ? cc : 0.f;
        }
        effL[idx] = e;
        tsum += e;
    }
    #pragma unroll
    for (int off = 1; off < 64; off <<= 1) tsum += __shfl_xor(tsum, off);
    if (lane == 0) rb[wv] = tsum;
    __syncthreads();
    if (tid == 0) atomicAdd(&ti[b], rb[0] + rb[1] + rb[2] + rb[3]);

    f32x16 a0, a1, a2, a3;
    #pragma unroll
    for (int r = 0; r < 16; ++r) { a0[r] = 0.f; a1[r] = 0.f; a2[r] = 0.f; a3[r] = 0.f; }

    const int ml = tid & 63, dgrp = tid >> 6;
    #pragma unroll 1
    for (int t = 0; t < GM_CH / 64; ++t) {
        const int mt0 = m0 + t * 64;
        __syncthreads();
        const float em = effL[t * 64 + ml];
        const int m = mt0 + ml;
        const bool ok = m < M_TOT;
        const unsigned short* mrow = mnb + (size_t)m * DD;
        #pragma unroll 8
        for (int i = 0; i < 32; ++i) {
            int d = dgrp * 32 + i;
            unsigned short u = ok ? mrow[d] : (unsigned short)0;
            int us = d * 64 + (ml ^ ((d & 7) << 3));
            Bt[us] = u;
            At[us] = f2bf(bf2f(u) * em);
        }
        __syncthreads();
        #pragma unroll
        for (int kk = 0; kk < 4; ++kk) {
            int mo = kk * 16 + h * 8;
            bf16x8 Afr = *(const bf16x8*)&At[(wv * 32 + c) * 64 + (mo ^ ((c & 7) << 3))];
            bf16x8 B0 = *(const bf16x8*)&Bt[(0 * 32 + c) * 64 + (mo ^ ((c & 7) << 3))];
            bf16x8 B1 = *(const bf16x8*)&Bt[(1 * 32 + c) * 64 + (mo ^ ((c & 7) << 3))];
            bf16x8 B2 = *(const bf16x8*)&Bt[(2 * 32 + c) * 64 + (mo ^ ((c & 7) << 3))];
            bf16x8 B3 = *(const bf16x8*)&Bt[(3 * 32 + c) * 64 + (mo ^ ((c & 7) << 3))];
            a0 = __builtin_amdgcn_mfma_f32_32x32x16_bf16(Afr, B0, a0, 0, 0, 0);
            a1 = __builtin_amdgcn_mfma_f32_32x32x16_bf16(Afr, B1, a1, 0, 0, 0);
            a2 = __builtin_amdgcn_mfma_f32_32x32x16_bf16(Afr, B2, a2, 0, 0, 0);
            a3 = __builtin_amdgcn_mfma_f32_32x32x16_bf16(Afr, B3, a3, 0, 0, 0);
        }
    }
    float* o = pG + (size_t)(blockIdx.x * BB + b) * (DD * DD);
    #pragma unroll
    for (int r = 0; r < 16; ++r) {
        int rf = (r & 3) + 8 * (r >> 2) + 4 * h;
        o[(wv * 32 + rf) * DD + 0 * 32 + c] = a0[r];
        o[(wv * 32 + rf) * DD + 1 * 32 + c] = a1[r];
        o[(wv * 32 + rf) * DD + 2 * 32 + c] = a2[r];
        o[(wv * 32 + rf) * DD + 3 * 32 + c] = a3[r];
    }
}

// ---------------- gmat stage 2: reduce partials -> G ----------------
__global__ __launch_bounds__(256) void k_gmat2(const float* __restrict__ pG,
                                               float* __restrict__ G) {
    const int b = blockIdx.y;
    const int i = (blockIdx.x * 256 + threadIdx.x) * 4;
    float4 s = make_float4(0.f, 0.f, 0.f, 0.f);
    for (int c = 0; c < GM_NCH; ++c) {
        float4 p = *(const float4*)&pG[(size_t)(c * BB + b) * (DD * DD) + i];
        s.x += p.x; s.y += p.y; s.z += p.z; s.w += p.w;
    }
    *(float4*)&G[(size_t)b * (DD * DD) + i] = s;
}

// ---------------- final = raw + scale * raw @ G_b ----------------
__global__ __launch_bounds__(256) void k_final(
    const float* __restrict__ raw, const float* __restrict__ Gmat,
    const float* __restrict__ ti, float* __restrict__ out) {
    __shared__ float Gl[DD * DD];
    __shared__ float rawl[32 * DD];
    const int tid = threadIdx.x;
    const int b = blockIdx.y;
    const int s0 = blockIdx.x * 32;
    const float4* Gv = (const float4*)(Gmat + (size_t)b * DD * DD);
    #pragma unroll
    for (int i = 0; i < 16; ++i) ((float4*)Gl)[tid + i * 256] = Gv[tid + i * 256];
    const float4* rv = (const float4*)(raw + ((size_t)b * SS + s0) * DD);
    #pragma unroll
    for (int i = 0; i < 4; ++i) ((float4*)rawl)[tid + i * 256] = rv[tid + i * 256];
    __syncthreads();
    float tib = ti[b];
    float scale = (tib > 0.01f) ? 0.5f / (tib + 1e-5f) : 0.0f;
    const int dq = tid & 31;
    const int sg = tid >> 5;
    const float4* Gl4 = (const float4*)Gl;
    #pragma unroll 1
    for (int t = 0; t < 4; ++t) {
        int s = sg + t * 8;
        float4 acc = make_float4(0.f, 0.f, 0.f, 0.f);
        #pragma unroll
        for (int k = 0; k < DD; ++k) {
            float r = rawl[s * DD + k];
            float4 gv = Gl4[k * 32 + dq];
            acc.x += r * gv.x; acc.y += r * gv.y;
            acc.z += r * gv.z; acc.w += r * gv.w;
        }
        float4 rw = ((const float4*)rawl)[s * 32 + dq];
        float4 o = make_float4(rw.x + scale * acc.x, rw.y + scale * acc.y,
                               rw.z + scale * acc.z, rw.w + scale * acc.w);
        ((float4*)(out + ((size_t)b * SS + s0) * DD))[s * 32 + dq] = o;
    }
}

extern "C" void kernel_launch(void* const* d_in, const int* in_sizes, int n_in,
                              void* d_out, int out_size, void* d_ws, size_t ws_size,
                              hipStream_t stream) {
    const float* x   = (const float*)d_in[0];
    const float* mem = (const float*)d_in[1];
    const float* W1  = (const float*)d_in[2];
    const float* b1  = (const float*)d_in[3];
    const float* lg  = (const float*)d_in[4];
    const float* lb  = (const float*)d_in[5];
    const float* W2  = (const float*)d_in[6];
    const float* b2  = (const float*)d_in[7];
    float* out = (float*)d_out;

    float* wsf = (float*)d_ws;
    size_t off = 0;
    unsigned short* mnb = (unsigned short*)(wsf + off); off += (size_t)M_PAD * 64;
    float* norm_sq = wsf + off;                         off += M_PAD;
    unsigned short* xnb = (unsigned short*)(wsf + off); off += (size_t)BB * SS * 64;
    float* raw = wsf + off;                             off += (size_t)BB * SS * DD;
    float* cw  = wsf + off;                             off += (size_t)BB * M_PAD;
    float* G   = wsf + off;                             off += (size_t)BB * DD * DD;
    float* ti  = wsf + off;                             off += BB;
    unsigned short* w1b = (unsigned short*)(wsf + off); off += DD * DD / 2;
    unsigned short* w2b = (unsigned short*)(wsf + off); off += DD * DD / 2;
    float* pG  = wsf + off;                             off += (size_t)GM_NCH * BB * DD * DD;

    k_prep_mem<<<dim3(M_PAD / 4), 256, 0, stream>>>(mem, mnb, norm_sq, ti, cw,
                                                    W1, W2, w1b, w2b);
    k_fmlp<<<dim3(SS * BB / 32), 256, 0, stream>>>(x, w1b, b1, lg, lb, w2b, b2, xnb, raw);
    k_cw<<<dim3(M_PAD / 256, 2, BB), 256, 0, stream>>>(xnb, mnb, cw);
    k_gmatm<<<dim3(GM_NCH, BB), 256, 0, stream>>>(mnb, cw, norm_sq, ti, pG);
    k_gmat2<<<dim3(DD * DD / 1024, BB), 256, 0, stream>>>(pG, G);
    k_final<<<dim3(SS / 32, BB), 256, 0, stream>>>(raw, G, ti, out);
}

// Round 7
// 81.720 us; speedup vs baseline: 14.7793x; 1.1328x over previous
//
#include <hip/hip_runtime.h>

#define DD 128
#define SS 1024
#define BB 4
#define M_TOT 20000
#define M_PAD 20480   // 320*64 = 64 chunks * 320
#define GM_NCH 64
#define GM_CH 320
#define FMLP_BLOCKS 128
#define PREP_BLOCKS 320   // M_PAD/64

typedef __bf16 bf16x8 __attribute__((ext_vector_type(8)));
typedef unsigned short u16x8 __attribute__((ext_vector_type(8)));
typedef float f32x16 __attribute__((ext_vector_type(16)));

union BF8 { bf16x8 b; u16x8 u; };

__device__ __forceinline__ unsigned short f2bf(float f) {
    unsigned int u = __float_as_uint(f);
    u += 0x7FFFu + ((u >> 16) & 1u);
    return (unsigned short)(u >> 16);
}
__device__ __forceinline__ float bf2f(unsigned short h) {
    return __uint_as_float(((unsigned int)h) << 16);
}

// ---------------- k_front: fused {MLP+xnb} (blocks 0..127) and
// ---------------- {mem prep: mnb, mnT, norm_sq; zero cw,ti} (blocks 128..447)
__global__ __launch_bounds__(256) void k_front(
    const float* __restrict__ x, const float* __restrict__ W1,
    const float* __restrict__ b1, const float* __restrict__ ln_g,
    const float* __restrict__ ln_b, const float* __restrict__ W2,
    const float* __restrict__ b2, const float* __restrict__ mem,
    unsigned short* __restrict__ xnb, float* __restrict__ raw,
    unsigned short* __restrict__ mnb, unsigned short* __restrict__ mnT,
    float* __restrict__ norm_sq, float* __restrict__ ti,
    float* __restrict__ cw) {
    __shared__ __align__(16) char smem_raw[64 * 136 * 2];   // 17408 B shared by branches
    const int tid = threadIdx.x;
    const int bid = blockIdx.x;

    if (bid < FMLP_BLOCKS) {
        // ================= MLP branch =================
        unsigned short* featsL = (unsigned short*)smem_raw;        // 32*136 u16
        float* redp = (float*)(smem_raw + 8704);                   // [4][32][2] floats
        float2* stats = (float2*)(smem_raw + 8704 + 1024);         // 32 float2
        const int lane = tid & 63, wv = tid >> 6;
        const int col = lane & 31, hi = lane >> 5;
        const int t0 = bid * 32;
        const int ct = wv;

        bf16x8 Af[8];
        float sq = 0.f;
        const float* xrow = x + (size_t)(t0 + col) * DD + hi * 8;
        #pragma unroll
        for (int kk = 0; kk < 8; ++kk) {
            float4 p = *(const float4*)(xrow + kk * 16);
            float4 q = *(const float4*)(xrow + kk * 16 + 4);
            BF8 t;
            t.u[0] = f2bf(p.x); t.u[1] = f2bf(p.y); t.u[2] = f2bf(p.z); t.u[3] = f2bf(p.w);
            t.u[4] = f2bf(q.x); t.u[5] = f2bf(q.y); t.u[6] = f2bf(q.z); t.u[7] = f2bf(q.w);
            Af[kk] = t.b;
            sq += p.x * p.x + p.y * p.y + p.z * p.z + p.w * p.w;
            sq += q.x * q.x + q.y * q.y + q.z * q.z + q.w * q.w;
        }
        sq += __shfl_xor(sq, 32);
        float xrs = rsqrtf(sq + 1e-12f);
        if (wv == 0) {
            unsigned short* xo = xnb + (size_t)(t0 + col) * DD + hi * 8;
            #pragma unroll
            for (int kk = 0; kk < 8; ++kk) {
                BF8 t; t.b = Af[kk];
                u16x8 o;
                #pragma unroll
                for (int j = 0; j < 8; ++j) o[j] = f2bf(bf2f(t.u[j]) * xrs);
                *(u16x8*)(xo + kk * 16) = o;
            }
        }

        f32x16 acc;
        {
            float bv = b1[ct * 32 + col];
            #pragma unroll
            for (int r = 0; r < 16; ++r) acc[r] = bv;
        }
        const float* w1row = W1 + (size_t)(ct * 32 + col) * DD + hi * 8;
        #pragma unroll
        for (int kk = 0; kk < 8; ++kk) {
            float4 p = *(const float4*)(w1row + kk * 16);
            float4 q = *(const float4*)(w1row + kk * 16 + 4);
            BF8 t;
            t.u[0] = f2bf(p.x); t.u[1] = f2bf(p.y); t.u[2] = f2bf(p.z); t.u[3] = f2bf(p.w);
            t.u[4] = f2bf(q.x); t.u[5] = f2bf(q.y); t.u[6] = f2bf(q.z); t.u[7] = f2bf(q.w);
            acc = __builtin_amdgcn_mfma_f32_32x32x16_bf16(Af[kk], t.b, acc, 0, 0, 0);
        }

        float rs_[16], rq_[16];
        #pragma unroll
        for (int r = 0; r < 16; ++r) { float v = acc[r]; rs_[r] = v; rq_[r] = v * v; }
        #pragma unroll
        for (int off = 1; off < 32; off <<= 1) {
            #pragma unroll
            for (int r = 0; r < 16; ++r) {
                rs_[r] += __shfl_xor(rs_[r], off);
                rq_[r] += __shfl_xor(rq_[r], off);
            }
        }
        if (col == 0) {
            #pragma unroll
            for (int r = 0; r < 16; ++r) {
                int row = (r & 3) + 8 * (r >> 2) + 4 * hi;
                redp[(wv * 32 + row) * 2 + 0] = rs_[r];
                redp[(wv * 32 + row) * 2 + 1] = rq_[r];
            }
        }
        __syncthreads();
        if (tid < 32) {
            float S = redp[(0 * 32 + tid) * 2] + redp[(1 * 32 + tid) * 2] +
                      redp[(2 * 32 + tid) * 2] + redp[(3 * 32 + tid) * 2];
            float Q = redp[(0 * 32 + tid) * 2 + 1] + redp[(1 * 32 + tid) * 2 + 1] +
                      redp[(2 * 32 + tid) * 2 + 1] + redp[(3 * 32 + tid) * 2 + 1];
            float mu = S * (1.f / 128.f);
            float rstd = rsqrtf(Q * (1.f / 128.f) - mu * mu + 1e-5f);
            stats[tid] = make_float2(mu, rstd);
        }
        __syncthreads();

        {
            float gv = ln_g[ct * 32 + col], bv = ln_b[ct * 32 + col];
            #pragma unroll
            for (int r = 0; r < 16; ++r) {
                int row = (r & 3) + 8 * (r >> 2) + 4 * hi;
                float2 st = stats[row];
                float v = fmaxf((acc[r] - st.x) * st.y * gv + bv, 0.f);
                featsL[row * 136 + ct * 32 + col] = f2bf(v);
            }
        }
        __syncthreads();

        f32x16 a2;
        {
            float bv = b2[ct * 32 + col];
            #pragma unroll
            for (int r = 0; r < 16; ++r) a2[r] = bv;
        }
        const float* w2row = W2 + (size_t)(ct * 32 + col) * DD + hi * 8;
        #pragma unroll
        for (int kk = 0; kk < 8; ++kk) {
            bf16x8 Aq = *(const bf16x8*)&featsL[(lane & 31) * 136 + hi * 8 + kk * 16];
            float4 p = *(const float4*)(w2row + kk * 16);
            float4 q = *(const float4*)(w2row + kk * 16 + 4);
            BF8 t;
            t.u[0] = f2bf(p.x); t.u[1] = f2bf(p.y); t.u[2] = f2bf(p.z); t.u[3] = f2bf(p.w);
            t.u[4] = f2bf(q.x); t.u[5] = f2bf(q.y); t.u[6] = f2bf(q.z); t.u[7] = f2bf(q.w);
            a2 = __builtin_amdgcn_mfma_f32_32x32x16_bf16(Aq, t.b, a2, 0, 0, 0);
        }
        #pragma unroll
        for (int r = 0; r < 16; ++r) {
            int row = (r & 3) + 8 * (r >> 2) + 4 * hi;
            raw[(size_t)(t0 + row) * DD + ct * 32 + col] = a2[r];
        }
    } else {
        // ================= prep branch: 64 mem rows per block =================
        unsigned short* RM = (unsigned short*)smem_raw;   // [64][136] u16
        const int pb = bid - FMLP_BLOCKS;                 // 0..319
        const int m0 = pb * 64;
        cw[pb * 256 + tid] = 0.0f;                        // 320*256 = BB*M_PAD
        if (pb == 0 && tid < BB) ti[tid] = 0.0f;

        const int r = tid >> 2, seg = tid & 3;            // 64 rows x 4 segs
        const int m = m0 + r;
        const bool ok = m < M_TOT;
        float4 v[8];
        const float4* src = (const float4*)mem + (size_t)m * 32 + seg * 8;
        #pragma unroll
        for (int i = 0; i < 8; ++i)
            v[i] = ok ? src[i] : make_float4(0.f, 0.f, 0.f, 0.f);
        float ss = 0.f;
        #pragma unroll
        for (int i = 0; i < 8; ++i)
            ss += v[i].x * v[i].x + v[i].y * v[i].y + v[i].z * v[i].z + v[i].w * v[i].w;
        ss += __shfl_xor(ss, 1);
        ss += __shfl_xor(ss, 2);
        float rs = rsqrtf(ss + 1e-12f);
        if (seg == 0) norm_sq[m] = ss;

        #pragma unroll
        for (int i = 0; i < 4; ++i) {
            float4 a = v[2 * i], bq = v[2 * i + 1];
            u16x8 o;
            o[0] = f2bf(a.x * rs); o[1] = f2bf(a.y * rs);
            o[2] = f2bf(a.z * rs); o[3] = f2bf(a.w * rs);
            o[4] = f2bf(bq.x * rs); o[5] = f2bf(bq.y * rs);
            o[6] = f2bf(bq.z * rs); o[7] = f2bf(bq.w * rs);
            *(u16x8*)(mnb + (size_t)m * DD + seg * 32 + i * 8) = o;
            *(u16x8*)(RM + r * 136 + seg * 32 + i * 8) = o;
        }
        __syncthreads();
        // transposed write: thread -> (d, half); lane pairs cover a full 128B line
        const int d = tid >> 1, half = tid & 1;
        unsigned short* dst = mnT + (size_t)d * M_PAD + m0 + half * 32;
        #pragma unroll
        for (int q = 0; q < 4; ++q) {
            u16x8 o;
            #pragma unroll
            for (int j = 0; j < 8; ++j)
                o[j] = RM[(half * 32 + q * 8 + j) * 136 + d];
            *(u16x8*)(dst + q * 8) = o;
        }
    }
}

// ---------------- cw: double-buffered LDS A-tile, B in regs, 4 s-quarters ----------------
__global__ __launch_bounds__(256, 3) void k_cw(
    const unsigned short* __restrict__ xnb, const unsigned short* __restrict__ mnb,
    float* __restrict__ cw) {
    __shared__ unsigned short As[2][32 * 128];
    const int tid = threadIdx.x, lane = tid & 63, wv = tid >> 6;
    const int c = lane & 31, h = lane >> 5;
    const int b = blockIdx.z;
    const int mw = blockIdx.x * 256 + wv * 64;
    const int s_base = blockIdx.y * 256;

    const int srow = tid >> 4, sk16 = tid & 15;
    const int soff = srow * 128 + ((sk16 * 8) ^ ((srow & 15) << 3));
    const int srow1 = (tid + 256) >> 4;
    const int soff1 = srow1 * 128 + ((sk16 * 8) ^ ((srow1 & 15) << 3));
    const unsigned short* xbase = xnb + ((size_t)b * SS + s_base) * DD;

    bf16x8 Bf[2][8];
    #pragma unroll
    for (int ct = 0; ct < 2; ++ct)
        #pragma unroll
        for (int kk = 0; kk < 8; ++kk)
            Bf[ct][kk] = *(const bf16x8*)(mnb + (size_t)(mw + ct * 32 + c) * DD +
                                          kk * 16 + h * 8);

    {
        u16x8 v0 = *(const u16x8*)(xbase + (size_t)srow * DD + sk16 * 8);
        u16x8 v1 = *(const u16x8*)(xbase + (size_t)srow1 * DD + sk16 * 8);
        *(u16x8*)&As[0][soff] = v0;
        *(u16x8*)&As[0][soff1] = v1;
    }

    float cw0 = 0.f, cw1 = 0.f;
    #pragma unroll 1
    for (int it = 0; it < 8; ++it) {
        __syncthreads();
        u16x8 v0, v1;
        if (it < 7) {
            const unsigned short* nb = xbase + (size_t)(it + 1) * 32 * DD;
            v0 = *(const u16x8*)(nb + (size_t)srow * DD + sk16 * 8);
            v1 = *(const u16x8*)(nb + (size_t)srow1 * DD + sk16 * 8);
        }
        f32x16 p0, p1;
        #pragma unroll
        for (int r = 0; r < 16; ++r) { p0[r] = 0.f; p1[r] = 0.f; }
        const unsigned short* Ab = As[it & 1];
        __builtin_amdgcn_s_setprio(1);
        #pragma unroll
        for (int kk = 0; kk < 8; ++kk) {
            bf16x8 Afr = *(const bf16x8*)&Ab[c * 128 + ((kk * 16 + h * 8) ^ ((c & 15) << 3))];
            p0 = __builtin_amdgcn_mfma_f32_32x32x16_bf16(Afr, Bf[0][kk], p0, 0, 0, 0);
            p1 = __builtin_amdgcn_mfma_f32_32x32x16_bf16(Afr, Bf[1][kk], p1, 0, 0, 0);
        }
        __builtin_amdgcn_s_setprio(0);
        if (it < 7) {
            unsigned short* An = As[(it + 1) & 1];
            *(u16x8*)&An[soff] = v0;
            *(u16x8*)&An[soff1] = v1;
        }
        #pragma unroll
        for (int r = 0; r < 16; ++r) {
            float a = p0[r], bb = p1[r];
            cw0 += a > 0.1f ? a : 0.f;
            cw1 += bb > 0.1f ? bb : 0.f;
        }
    }
    cw0 += __shfl_xor(cw0, 32);
    cw1 += __shfl_xor(cw1, 32);
    if (lane < 32) {
        atomicAdd(&cw[(size_t)b * M_PAD + mw + c], cw0);
        atomicAdd(&cw[(size_t)b * M_PAD + mw + 32 + c], cw1);
    }
}

// ---------------- gmat via MFMA from global mnT (both operands b128-contiguous) ----------------
// G_b = sum_m eff[b,m] * mn[m] mn[m]^T ; A = diag-scaled rows of mnT, B = raw mnT.
__global__ __launch_bounds__(256) void k_gmatm(
    const unsigned short* __restrict__ mnT, const float* __restrict__ cw,
    const float* __restrict__ norm_sq, float* __restrict__ ti,
    float* __restrict__ pG) {
    __shared__ float effL[GM_CH];
    __shared__ float rb[4];
    const int tid = threadIdx.x, lane = tid & 63, wv = tid >> 6;
    const int c = lane & 31, h = lane >> 5;
    const int b = blockIdx.y;
    const int m0 = blockIdx.x * GM_CH;

    float tsum = 0.f;
    #pragma unroll
    for (int idx = tid; idx < GM_CH; idx += 256) {
        int m = m0 + idx;
        float e = 0.f;
        if (m < M_TOT) {
            float cc = cw[(size_t)b * M_PAD + m];
            float ns = norm_sq[m];
            e = (cc > 0.01f && ns > 1e-6f) ? cc : 0.f;
        }
        effL[idx] = e;
        tsum += e;
    }
    #pragma unroll
    for (int off = 1; off < 64; off <<= 1) tsum += __shfl_xor(tsum, off);
    if (lane == 0) rb[wv] = tsum;
    __syncthreads();
    if (tid == 0) atomicAdd(&ti[b], rb[0] + rb[1] + rb[2] + rb[3]);

    f32x16 a0, a1, a2, a3;
    #pragma unroll
    for (int r = 0; r < 16; ++r) { a0[r] = 0.f; a1[r] = 0.f; a2[r] = 0.f; a3[r] = 0.f; }

    const unsigned short* Arow = mnT + (size_t)(wv * 32 + c) * M_PAD;
    const unsigned short* B0r = mnT + (size_t)(0 * 32 + c) * M_PAD;
    const unsigned short* B1r = mnT + (size_t)(1 * 32 + c) * M_PAD;
    const unsigned short* B2r = mnT + (size_t)(2 * 32 + c) * M_PAD;
    const unsigned short* B3r = mnT + (size_t)(3 * 32 + c) * M_PAD;

    #pragma unroll 1
    for (int t = 0; t < GM_CH / 64; ++t) {
        #pragma unroll
        for (int kk = 0; kk < 4; ++kk) {
            const int mo = m0 + t * 64 + kk * 16 + h * 8;
            const int eo = t * 64 + kk * 16 + h * 8;
            u16x8 au = *(const u16x8*)(Arow + mo);
            float4 e0 = *(float4*)&effL[eo];
            float4 e1 = *(float4*)&effL[eo + 4];
            BF8 af;
            af.u[0] = f2bf(bf2f(au[0]) * e0.x);
            af.u[1] = f2bf(bf2f(au[1]) * e0.y);
            af.u[2] = f2bf(bf2f(au[2]) * e0.z);
            af.u[3] = f2bf(bf2f(au[3]) * e0.w);
            af.u[4] = f2bf(bf2f(au[4]) * e1.x);
            af.u[5] = f2bf(bf2f(au[5]) * e1.y);
            af.u[6] = f2bf(bf2f(au[6]) * e1.z);
            af.u[7] = f2bf(bf2f(au[7]) * e1.w);
            bf16x8 B0 = *(const bf16x8*)(B0r + mo);
            bf16x8 B1 = *(const bf16x8*)(B1r + mo);
            bf16x8 B2 = *(const bf16x8*)(B2r + mo);
            bf16x8 B3 = *(const bf16x8*)(B3r + mo);
            a0 = __builtin_amdgcn_mfma_f32_32x32x16_bf16(af.b, B0, a0, 0, 0, 0);
            a1 = __builtin_amdgcn_mfma_f32_32x32x16_bf16(af.b, B1, a1, 0, 0, 0);
            a2 = __builtin_amdgcn_mfma_f32_32x32x16_bf16(af.b, B2, a2, 0, 0, 0);
            a3 = __builtin_amdgcn_mfma_f32_32x32x16_bf16(af.b, B3, a3, 0, 0, 0);
        }
    }
    float* o = pG + (size_t)(blockIdx.x * BB + b) * (DD * DD);
    #pragma unroll
    for (int r = 0; r < 16; ++r) {
        int rf = (r & 3) + 8 * (r >> 2) + 4 * h;
        o[(wv * 32 + rf) * DD + 0 * 32 + c] = a0[r];
        o[(wv * 32 + rf) * DD + 1 * 32 + c] = a1[r];
        o[(wv * 32 + rf) * DD + 2 * 32 + c] = a2[r];
        o[(wv * 32 + rf) * DD + 3 * 32 + c] = a3[r];
    }
}

// ---------------- gmat stage 2: reduce partials -> G (256 blocks) ----------------
__global__ __launch_bounds__(256) void k_gmat2(const float* __restrict__ pG,
                                               float* __restrict__ G) {
    __shared__ float4 redv[256];
    const int tid = threadIdx.x;
    const int b = blockIdx.y;
    const int f4i = blockIdx.x * 64 + (tid & 63);
    const int cg = tid >> 6;
    const float4* pG4 = (const float4*)pG;
    float4 s = make_float4(0.f, 0.f, 0.f, 0.f);
    for (int c = cg; c < GM_NCH; c += 4) {
        float4 p = pG4[(size_t)(c * BB + b) * (DD * DD / 4) + f4i];
        s.x += p.x; s.y += p.y; s.z += p.z; s.w += p.w;
    }
    redv[tid] = s;
    __syncthreads();
    if (tid < 64) {
        float4 r0 = redv[tid], r1 = redv[tid + 64], r2 = redv[tid + 128], r3 = redv[tid + 192];
        float4 o = make_float4(r0.x + r1.x + r2.x + r3.x, r0.y + r1.y + r2.y + r3.y,
                               r0.z + r1.z + r2.z + r3.z, r0.w + r1.w + r2.w + r3.w);
        ((float4*)G)[(size_t)b * (DD * DD / 4) + f4i] = o;
    }
}

// ---------------- final = raw + scale * raw @ G_b ----------------
__global__ __launch_bounds__(256) void k_final(
    const float* __restrict__ raw, const float* __restrict__ Gmat,
    const float* __restrict__ ti, float* __restrict__ out) {
    __shared__ float Gl[DD * DD];
    __shared__ float rawl[32 * DD];
    const int tid = threadIdx.x;
    const int b = blockIdx.y;
    const int s0 = blockIdx.x * 32;
    const float4* Gv = (const float4*)(Gmat + (size_t)b * DD * DD);
    #pragma unroll
    for (int i = 0; i < 16; ++i) ((float4*)Gl)[tid + i * 256] = Gv[tid + i * 256];
    const float4* rv = (const float4*)(raw + ((size_t)b * SS + s0) * DD);
    #pragma unroll
    for (int i = 0; i < 4; ++i) ((float4*)rawl)[tid + i * 256] = rv[tid + i * 256];
    __syncthreads();
    float tib = ti[b];
    float scale = (tib > 0.01f) ? 0.5f / (tib + 1e-5f) : 0.0f;
    const int dq = tid & 31;
    const int sg = tid >> 5;
    const float4* Gl4 = (const float4*)Gl;
    #pragma unroll 1
    for (int t = 0; t < 4; ++t) {
        int s = sg + t * 8;
        float4 acc = make_float4(0.f, 0.f, 0.f, 0.f);
        #pragma unroll
        for (int k = 0; k < DD; ++k) {
            float r = rawl[s * DD + k];
            float4 gv = Gl4[k * 32 + dq];
            acc.x += r * gv.x; acc.y += r * gv.y;
            acc.z += r * gv.z; acc.w += r * gv.w;
        }
        float4 rw = ((const float4*)rawl)[s * 32 + dq];
        float4 o = make_float4(rw.x + scale * acc.x, rw.y + scale * acc.y,
                               rw.z + scale * acc.z, rw.w + scale * acc.w);
        ((float4*)(out + ((size_t)b * SS + s0) * DD))[s * 32 + dq] = o;
    }
}

extern "C" void kernel_launch(void* const* d_in, const int* in_sizes, int n_in,
                              void* d_out, int out_size, void* d_ws, size_t ws_size,
                              hipStream_t stream) {
    const float* x   = (const float*)d_in[0];
    const float* mem = (const float*)d_in[1];
    const float* W1  = (const float*)d_in[2];
    const float* b1  = (const float*)d_in[3];
    const float* lg  = (const float*)d_in[4];
    const float* lb  = (const float*)d_in[5];
    const float* W2  = (const float*)d_in[6];
    const float* b2  = (const float*)d_in[7];
    float* out = (float*)d_out;

    float* wsf = (float*)d_ws;
    size_t off = 0;
    unsigned short* mnb = (unsigned short*)(wsf + off); off += (size_t)M_PAD * 64;
    unsigned short* mnT = (unsigned short*)(wsf + off); off += (size_t)M_PAD * 64;
    float* norm_sq = wsf + off;                         off += M_PAD;
    unsigned short* xnb = (unsigned short*)(wsf + off); off += (size_t)BB * SS * 64;
    float* raw = wsf + off;                             off += (size_t)BB * SS * DD;
    float* cw  = wsf + off;                             off += (size_t)BB * M_PAD;
    float* G   = wsf + off;                             off += (size_t)BB * DD * DD;
    float* ti  = wsf + off;                             off += BB;
    float* pG  = wsf + off;                             off += (size_t)GM_NCH * BB * DD * DD;

    k_front<<<dim3(FMLP_BLOCKS + PREP_BLOCKS), 256, 0, stream>>>(
        x, W1, b1, lg, lb, W2, b2, mem, xnb, raw, mnb, mnT, norm_sq, ti, cw);
    k_cw<<<dim3(M_PAD / 256, 4, BB), 256, 0, stream>>>(xnb, mnb, cw);
    k_gmatm<<<dim3(GM_NCH, BB), 256, 0, stream>>>(mnT, cw, norm_sq, ti, pG);
    k_gmat2<<<dim3(DD * DD / 256, BB), 256, 0, stream>>>(pG, G);
    k_final<<<dim3(SS / 32, BB), 256, 0, stream>>>(raw, G, ti, out);
}

// Round 8
// 78.484 us; speedup vs baseline: 15.3887x; 1.0412x over previous
//
#include <hip/hip_runtime.h>

#define DD 128
#define SS 1024
#define BB 4
#define M_TOT 20000
#define M_PAD 20480   // 64 chunks * 320
#define GM_NCH 64
#define GM_CH 320
#define FMLP_BLOCKS 128
#define PREP_BLOCKS 320   // M_PAD/64

typedef __bf16 bf16x8 __attribute__((ext_vector_type(8)));
typedef unsigned short u16x8 __attribute__((ext_vector_type(8)));
typedef float f32x16 __attribute__((ext_vector_type(16)));

union BF8 { bf16x8 b; u16x8 u; };

__device__ __forceinline__ unsigned short f2bf(float f) {
    unsigned int u = __float_as_uint(f);
    u += 0x7FFFu + ((u >> 16) & 1u);
    return (unsigned short)(u >> 16);
}
__device__ __forceinline__ float bf2f(unsigned short h) {
    return __uint_as_float(((unsigned int)h) << 16);
}

// ---------------- k_front: fused {MLP+xnb} (blocks 0..127) and
// ---------------- {mem prep: mnb, mnT, norm_sq; zero cw,ti} (blocks 128..447)
__global__ __launch_bounds__(256) void k_front(
    const float* __restrict__ x, const float* __restrict__ W1,
    const float* __restrict__ b1, const float* __restrict__ ln_g,
    const float* __restrict__ ln_b, const float* __restrict__ W2,
    const float* __restrict__ b2, const float* __restrict__ mem,
    unsigned short* __restrict__ xnb, float* __restrict__ raw,
    unsigned short* __restrict__ mnb, unsigned short* __restrict__ mnT,
    float* __restrict__ norm_sq, float* __restrict__ ti,
    float* __restrict__ cw) {
    __shared__ __align__(16) char smem_raw[64 * 136 * 2];
    const int tid = threadIdx.x;
    const int bid = blockIdx.x;

    if (bid < FMLP_BLOCKS) {
        // ================= MLP branch =================
        unsigned short* featsL = (unsigned short*)smem_raw;
        float* redp = (float*)(smem_raw + 8704);
        float2* stats = (float2*)(smem_raw + 8704 + 1024);
        const int lane = tid & 63, wv = tid >> 6;
        const int col = lane & 31, hi = lane >> 5;
        const int t0 = bid * 32;
        const int ct = wv;

        bf16x8 Af[8];
        float sq = 0.f;
        const float* xrow = x + (size_t)(t0 + col) * DD + hi * 8;
        #pragma unroll
        for (int kk = 0; kk < 8; ++kk) {
            float4 p = *(const float4*)(xrow + kk * 16);
            float4 q = *(const float4*)(xrow + kk * 16 + 4);
            BF8 t;
            t.u[0] = f2bf(p.x); t.u[1] = f2bf(p.y); t.u[2] = f2bf(p.z); t.u[3] = f2bf(p.w);
            t.u[4] = f2bf(q.x); t.u[5] = f2bf(q.y); t.u[6] = f2bf(q.z); t.u[7] = f2bf(q.w);
            Af[kk] = t.b;
            sq += p.x * p.x + p.y * p.y + p.z * p.z + p.w * p.w;
            sq += q.x * q.x + q.y * q.y + q.z * q.z + q.w * q.w;
        }
        sq += __shfl_xor(sq, 32);
        float xrs = rsqrtf(sq + 1e-12f);
        if (wv == 0) {
            unsigned short* xo = xnb + (size_t)(t0 + col) * DD + hi * 8;
            #pragma unroll
            for (int kk = 0; kk < 8; ++kk) {
                BF8 t; t.b = Af[kk];
                u16x8 o;
                #pragma unroll
                for (int j = 0; j < 8; ++j) o[j] = f2bf(bf2f(t.u[j]) * xrs);
                *(u16x8*)(xo + kk * 16) = o;
            }
        }

        f32x16 acc;
        {
            float bv = b1[ct * 32 + col];
            #pragma unroll
            for (int r = 0; r < 16; ++r) acc[r] = bv;
        }
        const float* w1row = W1 + (size_t)(ct * 32 + col) * DD + hi * 8;
        #pragma unroll
        for (int kk = 0; kk < 8; ++kk) {
            float4 p = *(const float4*)(w1row + kk * 16);
            float4 q = *(const float4*)(w1row + kk * 16 + 4);
            BF8 t;
            t.u[0] = f2bf(p.x); t.u[1] = f2bf(p.y); t.u[2] = f2bf(p.z); t.u[3] = f2bf(p.w);
            t.u[4] = f2bf(q.x); t.u[5] = f2bf(q.y); t.u[6] = f2bf(q.z); t.u[7] = f2bf(q.w);
            acc = __builtin_amdgcn_mfma_f32_32x32x16_bf16(Af[kk], t.b, acc, 0, 0, 0);
        }

        float rs_[16], rq_[16];
        #pragma unroll
        for (int r = 0; r < 16; ++r) { float v = acc[r]; rs_[r] = v; rq_[r] = v * v; }
        #pragma unroll
        for (int off = 1; off < 32; off <<= 1) {
            #pragma unroll
            for (int r = 0; r < 16; ++r) {
                rs_[r] += __shfl_xor(rs_[r], off);
                rq_[r] += __shfl_xor(rq_[r], off);
            }
        }
        if (col == 0) {
            #pragma unroll
            for (int r = 0; r < 16; ++r) {
                int row = (r & 3) + 8 * (r >> 2) + 4 * hi;
                redp[(wv * 32 + row) * 2 + 0] = rs_[r];
                redp[(wv * 32 + row) * 2 + 1] = rq_[r];
            }
        }
        __syncthreads();
        if (tid < 32) {
            float S = redp[(0 * 32 + tid) * 2] + redp[(1 * 32 + tid) * 2] +
                      redp[(2 * 32 + tid) * 2] + redp[(3 * 32 + tid) * 2];
            float Q = redp[(0 * 32 + tid) * 2 + 1] + redp[(1 * 32 + tid) * 2 + 1] +
                      redp[(2 * 32 + tid) * 2 + 1] + redp[(3 * 32 + tid) * 2 + 1];
            float mu = S * (1.f / 128.f);
            float rstd = rsqrtf(Q * (1.f / 128.f) - mu * mu + 1e-5f);
            stats[tid] = make_float2(mu, rstd);
        }
        __syncthreads();

        {
            float gv = ln_g[ct * 32 + col], bv = ln_b[ct * 32 + col];
            #pragma unroll
            for (int r = 0; r < 16; ++r) {
                int row = (r & 3) + 8 * (r >> 2) + 4 * hi;
                float2 st = stats[row];
                float v = fmaxf((acc[r] - st.x) * st.y * gv + bv, 0.f);
                featsL[row * 136 + ct * 32 + col] = f2bf(v);
            }
        }
        __syncthreads();

        f32x16 a2;
        {
            float bv = b2[ct * 32 + col];
            #pragma unroll
            for (int r = 0; r < 16; ++r) a2[r] = bv;
        }
        const float* w2row = W2 + (size_t)(ct * 32 + col) * DD + hi * 8;
        #pragma unroll
        for (int kk = 0; kk < 8; ++kk) {
            bf16x8 Aq = *(const bf16x8*)&featsL[(lane & 31) * 136 + hi * 8 + kk * 16];
            float4 p = *(const float4*)(w2row + kk * 16);
            float4 q = *(const float4*)(w2row + kk * 16 + 4);
            BF8 t;
            t.u[0] = f2bf(p.x); t.u[1] = f2bf(p.y); t.u[2] = f2bf(p.z); t.u[3] = f2bf(p.w);
            t.u[4] = f2bf(q.x); t.u[5] = f2bf(q.y); t.u[6] = f2bf(q.z); t.u[7] = f2bf(q.w);
            a2 = __builtin_amdgcn_mfma_f32_32x32x16_bf16(Aq, t.b, a2, 0, 0, 0);
        }
        #pragma unroll
        for (int r = 0; r < 16; ++r) {
            int row = (r & 3) + 8 * (r >> 2) + 4 * hi;
            raw[(size_t)(t0 + row) * DD + ct * 32 + col] = a2[r];
        }
    } else {
        // ================= prep branch: 64 mem rows per block =================
        unsigned short* RM = (unsigned short*)smem_raw;   // [64][136] u16
        const int pb = bid - FMLP_BLOCKS;                 // 0..319
        const int m0 = pb * 64;
        cw[pb * 256 + tid] = 0.0f;
        if (pb == 0 && tid < BB) ti[tid] = 0.0f;

        const int r = tid >> 2, seg = tid & 3;
        const int m = m0 + r;
        const bool ok = m < M_TOT;
        float4 v[8];
        const float4* src = (const float4*)mem + (size_t)m * 32 + seg * 8;
        #pragma unroll
        for (int i = 0; i < 8; ++i)
            v[i] = ok ? src[i] : make_float4(0.f, 0.f, 0.f, 0.f);
        float ss = 0.f;
        #pragma unroll
        for (int i = 0; i < 8; ++i)
            ss += v[i].x * v[i].x + v[i].y * v[i].y + v[i].z * v[i].z + v[i].w * v[i].w;
        ss += __shfl_xor(ss, 1);
        ss += __shfl_xor(ss, 2);
        float rs = rsqrtf(ss + 1e-12f);
        if (seg == 0) norm_sq[m] = ss;

        #pragma unroll
        for (int i = 0; i < 4; ++i) {
            float4 a = v[2 * i], bq = v[2 * i + 1];
            u16x8 o;
            o[0] = f2bf(a.x * rs); o[1] = f2bf(a.y * rs);
            o[2] = f2bf(a.z * rs); o[3] = f2bf(a.w * rs);
            o[4] = f2bf(bq.x * rs); o[5] = f2bf(bq.y * rs);
            o[6] = f2bf(bq.z * rs); o[7] = f2bf(bq.w * rs);
            *(u16x8*)(mnb + (size_t)m * DD + seg * 32 + i * 8) = o;
            *(u16x8*)(RM + r * 136 + seg * 32 + i * 8) = o;
        }
        __syncthreads();
        const int d = tid >> 1, half = tid & 1;
        unsigned short* dst = mnT + (size_t)d * M_PAD + m0 + half * 32;
        #pragma unroll
        for (int q = 0; q < 4; ++q) {
            u16x8 o;
            #pragma unroll
            for (int j = 0; j < 8; ++j)
                o[j] = RM[(half * 32 + q * 8 + j) * 136 + d];
            *(u16x8*)(dst + q * 8) = o;
        }
    }
}

// ---------------- cw: 4-buffer LDS, ONE barrier per 2 s-tiles ----------------
// grid (80 m-tiles, 4 s-quarters, BB). Wave owns 64 m (2 col-tiles, B in regs).
__global__ __launch_bounds__(256, 3) void k_cw(
    const unsigned short* __restrict__ xnb, const unsigned short* __restrict__ mnb,
    float* __restrict__ cw) {
    __shared__ unsigned short As[4][32 * 128];
    const int tid = threadIdx.x, lane = tid & 63, wv = tid >> 6;
    const int c = lane & 31, h = lane >> 5;
    const int b = blockIdx.z;
    const int mw = blockIdx.x * 256 + wv * 64;
    const int s_base = blockIdx.y * 256;

    const int srow = tid >> 4, sk16 = tid & 15;
    const int soff = srow * 128 + ((sk16 * 8) ^ ((srow & 15) << 3));
    const int srow1 = srow + 16;
    const int soff1 = srow1 * 128 + ((sk16 * 8) ^ ((srow1 & 15) << 3));
    const unsigned short* xbase = xnb + ((size_t)b * SS + s_base) * DD;

    bf16x8 Bf[2][8];
    #pragma unroll
    for (int ct = 0; ct < 2; ++ct)
        #pragma unroll
        for (int kk = 0; kk < 8; ++kk)
            Bf[ct][kk] = *(const bf16x8*)(mnb + (size_t)(mw + ct * 32 + c) * DD +
                                          kk * 16 + h * 8);

    // prologue: stage tiles 0 and 1
    {
        u16x8 a0 = *(const u16x8*)(xbase + (size_t)srow * DD + sk16 * 8);
        u16x8 a1 = *(const u16x8*)(xbase + (size_t)srow1 * DD + sk16 * 8);
        const unsigned short* n1 = xbase + (size_t)32 * DD;
        u16x8 b0 = *(const u16x8*)(n1 + (size_t)srow * DD + sk16 * 8);
        u16x8 b1 = *(const u16x8*)(n1 + (size_t)srow1 * DD + sk16 * 8);
        *(u16x8*)&As[0][soff] = a0; *(u16x8*)&As[0][soff1] = a1;
        *(u16x8*)&As[1][soff] = b0; *(u16x8*)&As[1][soff1] = b1;
    }

    float cw0 = 0.f, cw1 = 0.f;
    #pragma unroll 1
    for (int p = 0; p < 4; ++p) {
        __syncthreads();   // staged buffers ready; prior reads of target buffers done
        u16x8 w0, w1, w2, w3;
        if (p < 3) {
            const unsigned short* n0 = xbase + (size_t)(2 * p + 2) * 32 * DD;
            const unsigned short* n1 = xbase + (size_t)(2 * p + 3) * 32 * DD;
            w0 = *(const u16x8*)(n0 + (size_t)srow * DD + sk16 * 8);
            w1 = *(const u16x8*)(n0 + (size_t)srow1 * DD + sk16 * 8);
            w2 = *(const u16x8*)(n1 + (size_t)srow * DD + sk16 * 8);
            w3 = *(const u16x8*)(n1 + (size_t)srow1 * DD + sk16 * 8);
        }
        // ---- tile 2p ----
        {
            f32x16 p0, p1;
            #pragma unroll
            for (int r = 0; r < 16; ++r) { p0[r] = 0.f; p1[r] = 0.f; }
            const unsigned short* Ab = As[(2 * p) & 3];
            __builtin_amdgcn_s_setprio(1);
            #pragma unroll
            for (int kk = 0; kk < 8; ++kk) {
                bf16x8 Afr = *(const bf16x8*)&Ab[c * 128 + ((kk * 16 + h * 8) ^ ((c & 15) << 3))];
                p0 = __builtin_amdgcn_mfma_f32_32x32x16_bf16(Afr, Bf[0][kk], p0, 0, 0, 0);
                p1 = __builtin_amdgcn_mfma_f32_32x32x16_bf16(Afr, Bf[1][kk], p1, 0, 0, 0);
            }
            __builtin_amdgcn_s_setprio(0);
            #pragma unroll
            for (int r = 0; r < 16; ++r) {
                float a = p0[r], bb = p1[r];
                cw0 += a > 0.1f ? a : 0.f;
                cw1 += bb > 0.1f ? bb : 0.f;
            }
        }
        // ---- tile 2p+1 ----
        {
            f32x16 p0, p1;
            #pragma unroll
            for (int r = 0; r < 16; ++r) { p0[r] = 0.f; p1[r] = 0.f; }
            const unsigned short* Ab = As[(2 * p + 1) & 3];
            __builtin_amdgcn_s_setprio(1);
            #pragma unroll
            for (int kk = 0; kk < 8; ++kk) {
                bf16x8 Afr = *(const bf16x8*)&Ab[c * 128 + ((kk * 16 + h * 8) ^ ((c & 15) << 3))];
                p0 = __builtin_amdgcn_mfma_f32_32x32x16_bf16(Afr, Bf[0][kk], p0, 0, 0, 0);
                p1 = __builtin_amdgcn_mfma_f32_32x32x16_bf16(Afr, Bf[1][kk], p1, 0, 0, 0);
            }
            __builtin_amdgcn_s_setprio(0);
            if (p < 3) {
                unsigned short* An0 = As[(2 * p + 2) & 3];
                unsigned short* An1 = As[(2 * p + 3) & 3];
                *(u16x8*)&An0[soff] = w0; *(u16x8*)&An0[soff1] = w1;
                *(u16x8*)&An1[soff] = w2; *(u16x8*)&An1[soff1] = w3;
            }
            #pragma unroll
            for (int r = 0; r < 16; ++r) {
                float a = p0[r], bb = p1[r];
                cw0 += a > 0.1f ? a : 0.f;
                cw1 += bb > 0.1f ? bb : 0.f;
            }
        }
    }
    cw0 += __shfl_xor(cw0, 32);
    cw1 += __shfl_xor(cw1, 32);
    if (lane < 32) {
        atomicAdd(&cw[(size_t)b * M_PAD + mw + c], cw0);
        atomicAdd(&cw[(size_t)b * M_PAD + mw + 32 + c], cw1);
    }
}

// ---------------- gmat via MFMA from mnT, d-split across 2 blocks ----------------
// grid (GM_NCH, 2, BB) = 512 blocks. Block computes rows [half*64, half*64+64).
// Wave: row-tile = half*64 + (wv>>1)*32, col-tiles (wv&1)*2 + {0,1}.
__global__ __launch_bounds__(256) void k_gmatm(
    const unsigned short* __restrict__ mnT, const float* __restrict__ cw,
    const float* __restrict__ norm_sq, float* __restrict__ ti,
    float* __restrict__ pG) {
    __shared__ float effL[GM_CH];
    __shared__ float rb[4];
    const int tid = threadIdx.x, lane = tid & 63, wv = tid >> 6;
    const int c = lane & 31, h = lane >> 5;
    const int half = blockIdx.y;
    const int b = blockIdx.z;
    const int m0 = blockIdx.x * GM_CH;

    float tsum = 0.f;
    #pragma unroll
    for (int idx = tid; idx < GM_CH; idx += 256) {
        int m = m0 + idx;
        float e = 0.f;
        if (m < M_TOT) {
            float cc = cw[(size_t)b * M_PAD + m];
            float ns = norm_sq[m];
            e = (cc > 0.01f && ns > 1e-6f) ? cc : 0.f;
        }
        effL[idx] = e;
        tsum += e;
    }
    #pragma unroll
    for (int off = 1; off < 64; off <<= 1) tsum += __shfl_xor(tsum, off);
    if (lane == 0) rb[wv] = tsum;
    __syncthreads();
    if (half == 0 && tid == 0) atomicAdd(&ti[b], rb[0] + rb[1] + rb[2] + rb[3]);

    const int rbase = half * 64 + (wv >> 1) * 32;
    const int ct0 = (wv & 1) * 2;

    f32x16 a0, a1;
    #pragma unroll
    for (int r = 0; r < 16; ++r) { a0[r] = 0.f; a1[r] = 0.f; }

    const unsigned short* Arow = mnT + (size_t)(rbase + c) * M_PAD;
    const unsigned short* B0r = mnT + (size_t)((ct0 + 0) * 32 + c) * M_PAD;
    const unsigned short* B1r = mnT + (size_t)((ct0 + 1) * 32 + c) * M_PAD;

    #pragma unroll 1
    for (int t = 0; t < GM_CH / 64; ++t) {
        #pragma unroll
        for (int kk = 0; kk < 4; ++kk) {
            const int mo = m0 + t * 64 + kk * 16 + h * 8;
            const int eo = t * 64 + kk * 16 + h * 8;
            u16x8 au = *(const u16x8*)(Arow + mo);
            float4 e0 = *(float4*)&effL[eo];
            float4 e1 = *(float4*)&effL[eo + 4];
            BF8 af;
            af.u[0] = f2bf(bf2f(au[0]) * e0.x);
            af.u[1] = f2bf(bf2f(au[1]) * e0.y);
            af.u[2] = f2bf(bf2f(au[2]) * e0.z);
            af.u[3] = f2bf(bf2f(au[3]) * e0.w);
            af.u[4] = f2bf(bf2f(au[4]) * e1.x);
            af.u[5] = f2bf(bf2f(au[5]) * e1.y);
            af.u[6] = f2bf(bf2f(au[6]) * e1.z);
            af.u[7] = f2bf(bf2f(au[7]) * e1.w);
            bf16x8 B0 = *(const bf16x8*)(B0r + mo);
            bf16x8 B1 = *(const bf16x8*)(B1r + mo);
            a0 = __builtin_amdgcn_mfma_f32_32x32x16_bf16(af.b, B0, a0, 0, 0, 0);
            a1 = __builtin_amdgcn_mfma_f32_32x32x16_bf16(af.b, B1, a1, 0, 0, 0);
        }
    }
    float* o = pG + (size_t)(blockIdx.x * BB + b) * (DD * DD);
    #pragma unroll
    for (int r = 0; r < 16; ++r) {
        int rf = (r & 3) + 8 * (r >> 2) + 4 * h;
        o[(rbase + rf) * DD + (ct0 + 0) * 32 + c] = a0[r];
        o[(rbase + rf) * DD + (ct0 + 1) * 32 + c] = a1[r];
    }
}

// ---------------- gmat stage 2: reduce partials -> bf16 G ----------------
__global__ __launch_bounds__(256) void k_gmat2(const float* __restrict__ pG,
                                               unsigned short* __restrict__ Gb) {
    __shared__ float4 redv[256];
    const int tid = threadIdx.x;
    const int b = blockIdx.y;
    const int f4i = blockIdx.x * 64 + (tid & 63);
    const int cg = tid >> 6;
    const float4* pG4 = (const float4*)pG;
    float4 s = make_float4(0.f, 0.f, 0.f, 0.f);
    for (int c = cg; c < GM_NCH; c += 4) {
        float4 p = pG4[(size_t)(c * BB + b) * (DD * DD / 4) + f4i];
        s.x += p.x; s.y += p.y; s.z += p.z; s.w += p.w;
    }
    redv[tid] = s;
    __syncthreads();
    if (tid < 64) {
        float4 r0 = redv[tid], r1 = redv[tid + 64], r2 = redv[tid + 128], r3 = redv[tid + 192];
        ushort4 o;
        o.x = f2bf(r0.x + r1.x + r2.x + r3.x);
        o.y = f2bf(r0.y + r1.y + r2.y + r3.y);
        o.z = f2bf(r0.z + r1.z + r2.z + r3.z);
        o.w = f2bf(r0.w + r1.w + r2.w + r3.w);
        *(ushort4*)&Gb[(size_t)b * (DD * DD) + f4i * 4] = o;
    }
}

// ---------------- final = raw + scale * (raw @ G_b) via MFMA ----------------
// 128 blocks of 32 tokens; wave ct owns 32 output cols; zero LDS.
__global__ __launch_bounds__(256) void k_final(
    const float* __restrict__ raw, const unsigned short* __restrict__ Gb,
    const float* __restrict__ ti, float* __restrict__ out) {
    const int tid = threadIdx.x, lane = tid & 63, wv = tid >> 6;
    const int col = lane & 31, hi = lane >> 5;
    const int t0 = blockIdx.x * 32;          // global token base
    const int b = blockIdx.x >> 5;           // 32 blocks per batch
    const int ct = wv;

    bf16x8 Af[8];
    const float* rrow = raw + (size_t)(t0 + col) * DD + hi * 8;
    #pragma unroll
    for (int kk = 0; kk < 8; ++kk) {
        float4 p = *(const float4*)(rrow + kk * 16);
        float4 q = *(const float4*)(rrow + kk * 16 + 4);
        BF8 t;
        t.u[0] = f2bf(p.x); t.u[1] = f2bf(p.y); t.u[2] = f2bf(p.z); t.u[3] = f2bf(p.w);
        t.u[4] = f2bf(q.x); t.u[5] = f2bf(q.y); t.u[6] = f2bf(q.z); t.u[7] = f2bf(q.w);
        Af[kk] = t.b;
    }
    f32x16 acc;
    #pragma unroll
    for (int r = 0; r < 16; ++r) acc[r] = 0.f;
    const unsigned short* grow = Gb + (size_t)b * DD * DD + (size_t)(ct * 32 + col) * DD + hi * 8;
    #pragma unroll
    for (int kk = 0; kk < 8; ++kk) {
        bf16x8 Bw = *(const bf16x8*)(grow + kk * 16);
        acc = __builtin_amdgcn_mfma_f32_32x32x16_bf16(Af[kk], Bw, acc, 0, 0, 0);
    }
    float tib = ti[b];
    float scale = (tib > 0.01f) ? 0.5f / (tib + 1e-5f) : 0.0f;
    #pragma unroll
    for (int r = 0; r < 16; ++r) {
        int row = (r & 3) + 8 * (r >> 2) + 4 * hi;
        size_t idx = (size_t)(t0 + row) * DD + ct * 32 + col;
        out[idx] = raw[idx] + scale * acc[r];
    }
}

extern "C" void kernel_launch(void* const* d_in, const int* in_sizes, int n_in,
                              void* d_out, int out_size, void* d_ws, size_t ws_size,
                              hipStream_t stream) {
    const float* x   = (const float*)d_in[0];
    const float* mem = (const float*)d_in[1];
    const float* W1  = (const float*)d_in[2];
    const float* b1  = (const float*)d_in[3];
    const float* lg  = (const float*)d_in[4];
    const float* lb  = (const float*)d_in[5];
    const float* W2  = (const float*)d_in[6];
    const float* b2  = (const float*)d_in[7];
    float* out = (float*)d_out;

    float* wsf = (float*)d_ws;
    size_t off = 0;
    unsigned short* mnb = (unsigned short*)(wsf + off); off += (size_t)M_PAD * 64;
    unsigned short* mnT = (unsigned short*)(wsf + off); off += (size_t)M_PAD * 64;
    float* norm_sq = wsf + off;                         off += M_PAD;
    unsigned short* xnb = (unsigned short*)(wsf + off); off += (size_t)BB * SS * 64;
    float* raw = wsf + off;                             off += (size_t)BB * SS * DD;
    float* cw  = wsf + off;                             off += (size_t)BB * M_PAD;
    unsigned short* Gb = (unsigned short*)(wsf + off);  off += (size_t)BB * DD * DD / 2;
    float* ti  = wsf + off;                             off += BB;
    float* pG  = wsf + off;                             off += (size_t)GM_NCH * BB * DD * DD;

    k_front<<<dim3(FMLP_BLOCKS + PREP_BLOCKS), 256, 0, stream>>>(
        x, W1, b1, lg, lb, W2, b2, mem, xnb, raw, mnb, mnT, norm_sq, ti, cw);
    k_cw<<<dim3(M_PAD / 256, 4, BB), 256, 0, stream>>>(xnb, mnb, cw);
    k_gmatm<<<dim3(GM_NCH, 2, BB), 256, 0, stream>>>(mnT, cw, norm_sq, ti, pG);
    k_gmat2<<<dim3(DD * DD / 256, BB), 256, 0, stream>>>(pG, Gb);
    k_final<<<dim3(SS * BB / 32), 256, 0, stream>>>(raw, Gb, ti, out);
}